// Round 5
// baseline (2365.949 us; speedup 1.0000x reference)
//
#include <hip/hip_runtime.h>

// ---------------------------------------------------------------------------
// GCN encoder, bf16 staging + MFMA GEMMs + XCD-sliced PUSH aggregation.
//   h  = relu(Agg(x@W1) + b1);  [mu|lv] = Agg(h@[Wmu|Wlv]) + bias
// Agg(p)[i] = dinv[i] * ( sum_{e: dst=i} p'[src] + p'[i] ), p' = p*dinv[row]
// dinv[src] folded into GEMM epilogue.
// Staged activations are SLICE-MAJOR: p[slice][node][16ch] (16 bf16 = 32B).
// Slice s is processed only by WGs with blockIdx%8==s -> XCD s (round-robin
// WG->XCD dispatch). Per-XCD working set = contiguous 3.2MB < 4MiB L2
// (R4 verified: FETCH 661->81MB). R4's pull-gather was latency-serialized
// (bpermute->load chains, 85us); now: EDGE-PARALLEL push. One WG per
// (bucket,slice): stream the bucket's dst-binned edge list (2 lanes/edge,
// dwordx4 = full 32B slice row) and atomicAdd into an LDS accumulator
// [128 nodes][17-padded f32]. No bpermute, no max-degree idle slots, 4x
// fewer VMEM instrs, independent iterations -> loads pipeline.
// CSR build: LDS radix binning (bucket = dst>>7), zero global atomics.
// Requires n <= 131072 (n = 100000 here).
// ---------------------------------------------------------------------------

#define C_IN  256
#define HID   128
#define C_OUT 64
#define NBUCK 1024
#define P1WGS 256

typedef __attribute__((ext_vector_type(8))) short bf16x8;
typedef __attribute__((ext_vector_type(4))) float f32x4;

__device__ inline unsigned short f2bf(float f) {  // round-to-nearest-even
  unsigned u = __float_as_uint(f);
  unsigned r = u + 0x7FFF + ((u >> 16) & 1);
  return (unsigned short)(r >> 16);
}
__device__ inline float bflo(unsigned v) { return __uint_as_float(v << 16); }
__device__ inline float bfhi(unsigned v) { return __uint_as_float(v & 0xFFFF0000u); }

// ---------------- P1: per-WG bucket histogram (LDS atomics only) -------------
__global__ __launch_bounds__(256) void k_bin_count(const int* __restrict__ dst,
                                                   int* __restrict__ histmat, int E) {
  __shared__ int h[NBUCK];
  int tid = threadIdx.x;
  for (int i = tid; i < NBUCK; i += 256) h[i] = 0;
  __syncthreads();
  for (int e = blockIdx.x * 256 + tid; e < E; e += P1WGS * 256)
    atomicAdd(&h[dst[e] >> 7], 1);
  __syncthreads();
  for (int i = tid; i < NBUCK; i += 256)
    histmat[blockIdx.x * NBUCK + i] = h[i];
}

// ---------------- P2: per-bucket exclusive scan across WGs (in place) --------
__global__ __launch_bounds__(256) void k_col_scan(int* __restrict__ histmat,
                                                  int* __restrict__ bucket_tot) {
  __shared__ int sh[P1WGS];
  int b = blockIdx.x;
  int t = threadIdx.x;
  int v = histmat[t * NBUCK + b];
  sh[t] = v; __syncthreads();
  for (int ofs = 1; ofs < P1WGS; ofs <<= 1) {
    int add = (t >= ofs) ? sh[t - ofs] : 0;
    __syncthreads();
    sh[t] += add;
    __syncthreads();
  }
  histmat[t * NBUCK + b] = sh[t] - v;  // exclusive
  if (t == P1WGS - 1) bucket_tot[b] = sh[t];
}

// ---------------- P3: bucket_start = exclusive scan of bucket_tot ------------
__global__ void k_bucket_scan(const int* __restrict__ bucket_tot,
                              int* __restrict__ bucket_start, int E) {
  __shared__ int sh[NBUCK];
  int t = threadIdx.x;
  int v = bucket_tot[t];
  sh[t] = v; __syncthreads();
  for (int ofs = 1; ofs < NBUCK; ofs <<= 1) {
    int add = (t >= ofs) ? sh[t - ofs] : 0;
    __syncthreads();
    sh[t] += add;
    __syncthreads();
  }
  bucket_start[t] = sh[t] - v;
  if (t == NBUCK - 1) bucket_start[NBUCK] = E;
}

// ---------------- P4: scatter edges into bucket-segmented array --------------
__global__ __launch_bounds__(256) void k_bin_scatter(const int* __restrict__ src,
                                                     const int* __restrict__ dst,
                                                     const int* __restrict__ histmat,
                                                     const int* __restrict__ bucket_start,
                                                     unsigned* __restrict__ binned, int E) {
  __shared__ int cur[NBUCK];
  int tid = threadIdx.x;
  for (int i = tid; i < NBUCK; i += 256)
    cur[i] = bucket_start[i] + histmat[blockIdx.x * NBUCK + i];
  __syncthreads();
  for (int e = blockIdx.x * 256 + tid; e < E; e += P1WGS * 256) {
    int d = dst[e];
    int pos = atomicAdd(&cur[d >> 7], 1);
    binned[pos] = (unsigned)src[e] | ((unsigned)(d & 127) << 17);
  }
}

// ---------------- P5: per-bucket degree -> dinv ------------------------------
__global__ __launch_bounds__(256) void k_bucket_deg(const unsigned* __restrict__ binned,
                                                    const int* __restrict__ bucket_start,
                                                    float* __restrict__ dinv, int n) {
  __shared__ int h[128];
  int b = blockIdx.x, t = threadIdx.x;
  int start = bucket_start[b], end = bucket_start[b + 1];
  if (t < 128) h[t] = 0;
  __syncthreads();
  for (int e = start + t; e < end; e += 256)
    atomicAdd(&h[binned[e] >> 17], 1);
  __syncthreads();
  if (t < 128) {
    int node = b * 128 + t;
    if (node < n) dinv[node] = rsqrtf((float)h[t] + 1.0f);
  }
}

// ---------------- weight pre-swizzle -----------------------------------------
// Bswz[s][t][L][j] = bf16( B[s*32 + (L>>4)*8 + j][t*16 + (L&15)] )
__global__ void k_prep(const float* __restrict__ W1, const float* __restrict__ Wmu,
                       const float* __restrict__ Wlv,
                       unsigned short* __restrict__ bswz1,
                       unsigned short* __restrict__ bswz2) {
  int idx = blockIdx.x * 256 + threadIdx.x;
  if (idx < 4096) {            // W1: (256/32)*8*64
    int L = idx & 63, t = (idx >> 6) & 7, s = idx >> 9;
    const float* srcp = W1 + (size_t)(s * 32 + ((L >> 4) << 3)) * 128 + t * 16 + (L & 15);
    unsigned short* dstp = bswz1 + (size_t)idx * 8;
#pragma unroll
    for (int j = 0; j < 8; j++) dstp[j] = f2bf(srcp[(size_t)j * 128]);
  } else if (idx < 6144) {     // [Wmu|Wlv]: (128/32)*8*64
    int id2 = idx - 4096;
    int L = id2 & 63, t = (id2 >> 6) & 7, s = id2 >> 9;
    int nn = t * 16 + (L & 15);
    int k0 = s * 32 + ((L >> 4) << 3);
    const float* W = (nn < C_OUT) ? (Wmu + nn) : (Wlv + (nn - C_OUT));
    unsigned short* dstp = bswz2 + (size_t)id2 * 8;
#pragma unroll
    for (int j = 0; j < 8; j++) dstp[j] = f2bf(W[(size_t)(k0 + j) * C_OUT]);
  }
}

// -------- MFMA GEMM: C[slice][row][16](bf16) = (A @ B) * dinv[row] -----------
// A: float row-major [M][K] (layer 1) or bf16 slice-major [K/16][rows][16]
// (layer 2). C always slice-major with row stride `rows`.
template <typename AT, int K>
__global__ __launch_bounds__(256) void k_gemm_mfma(const AT* __restrict__ A,
                                                   const unsigned short* __restrict__ bswz,
                                                   unsigned short* __restrict__ C,
                                                   const float* __restrict__ dinv,
                                                   int M, int rows) {
  constexpr int NS = K / 32;
  int wave = threadIdx.x >> 6, lane = threadIdx.x & 63;
  int m0 = blockIdx.x * 64 + wave * 16;
  int lrow = lane & 15, lq = lane >> 4;
  int arow = m0 + lrow;
  bool rv = arow < M;
  int arow_c = rv ? arow : 0;

  auto loadA = [&](int s) -> bf16x8 {
    if (sizeof(AT) == 4) {     // row-major f32
      const float* af = (const float*)A + (size_t)arow_c * K + lq * 8 + s * 32;
      float4 u0 = rv ? *(const float4*)(af) : float4{0, 0, 0, 0};
      float4 u1 = rv ? *(const float4*)(af + 4) : float4{0, 0, 0, 0};
      union { unsigned short us[8]; bf16x8 v; } tmp;
      tmp.us[0] = f2bf(u0.x); tmp.us[1] = f2bf(u0.y);
      tmp.us[2] = f2bf(u0.z); tmp.us[3] = f2bf(u0.w);
      tmp.us[4] = f2bf(u1.x); tmp.us[5] = f2bf(u1.y);
      tmp.us[6] = f2bf(u1.z); tmp.us[7] = f2bf(u1.w);
      return tmp.v;
    } else {                   // bf16 slice-major: channels c0..c0+7, c0%16 in {0,8}
      int c0 = lq * 8 + s * 32;
      const unsigned short* ab = (const unsigned short*)A +
          ((size_t)(c0 >> 4) * rows + arow_c) * 16 + (c0 & 15);
      return rv ? *(const bf16x8*)(ab) : (bf16x8)(short)0;
    }
  };

  f32x4 acc[8];
#pragma unroll
  for (int t = 0; t < 8; t++) acc[t] = (f32x4){0.f, 0.f, 0.f, 0.f};

  bf16x8 a_cur = loadA(0);
  bf16x8 b_cur[8];
#pragma unroll
  for (int t = 0; t < 8; t++)
    b_cur[t] = *(const bf16x8*)(bswz + lane * 8 + t * 512);

#pragma unroll
  for (int s = 0; s < NS; ++s) {
    bf16x8 a_nxt = a_cur;
    bf16x8 b_nxt[8];
    if (s + 1 < NS) {
      a_nxt = loadA(s + 1);
      const unsigned short* bp = bswz + (size_t)(s + 1) * 4096 + lane * 8;
#pragma unroll
      for (int t = 0; t < 8; t++) b_nxt[t] = *(const bf16x8*)(bp + t * 512);
    }
#pragma unroll
    for (int t = 0; t < 8; t++)
      acc[t] = __builtin_amdgcn_mfma_f32_16x16x32_bf16(a_cur, b_cur[t], acc[t], 0, 0, 0);
    a_cur = a_nxt;
    if (s + 1 < NS) {
#pragma unroll
      for (int t = 0; t < 8; t++) b_cur[t] = b_nxt[t];
    }
  }
#pragma unroll
  for (int i = 0; i < 4; i++) {
    int rr = m0 + lq * 4 + i;
    if (rr < M) {
      float dsc = dinv[rr];           // fold dinv[src] into staged rows
#pragma unroll
      for (int t = 0; t < 8; t++)     // channel t*16+lrow -> slice t, pos lrow
        C[((size_t)t * rows + rr) * 16 + lrow] = f2bf(acc[t][i] * dsc);
    }
  }
}

// ---------------- PUSH aggregation: edge-parallel, LDS accumulate ------------
// One WG per (bucket, slice). slice = blockIdx%8 -> XCD. 2 lanes/edge load
// the full 32B slice row (dwordx4) and atomicAdd 8 floats into the bucket's
// LDS accumulator [128][ASTR]. Epilogue adds self-edge, scales, biases.
#define ASTR 17  // padded stride (f32) -> LDS banks spread for random ldst

#define AGG_PUSH_BODY                                                               \
  int tid = threadIdx.x;                                                            \
  int b = blockIdx.x >> 3;                                                          \
  int slice = blockIdx.x & 7;            /* slice == XCD (round-robin) */           \
  int start = bucket_st[b], end = bucket_st[b + 1];                                 \
  __shared__ float accs[128 * ASTR];                                                \
  for (int i = tid; i < 128 * ASTR; i += 256) accs[i] = 0.f;                        \
  __syncthreads();                                                                  \
  const unsigned* psl = (const unsigned*)p + (size_t)slice * (size_t)(n + 1) * 8;   \
  int half = tid & 1;                                                               \
  for (int e = start + (tid >> 1); e < end; e += 128) {                             \
    unsigned v = binned[e];                                                         \
    unsigned srow = v & 0x1FFFFu;                                                   \
    int ldst = (int)(v >> 17) & 127;                                                \
    uint4 q = *(const uint4*)(psl + srow * 8u + (unsigned)half * 4u);               \
    float* a = &accs[ldst * ASTR + half * 8];                                       \
    atomicAdd(a + 0, bflo(q.x)); atomicAdd(a + 1, bfhi(q.x));                       \
    atomicAdd(a + 2, bflo(q.y)); atomicAdd(a + 3, bfhi(q.y));                       \
    atomicAdd(a + 4, bflo(q.z)); atomicAdd(a + 5, bfhi(q.z));                       \
    atomicAdd(a + 6, bflo(q.w)); atomicAdd(a + 7, bfhi(q.w));                       \
  }                                                                                 \
  __syncthreads();                                                                  \
  int t = tid >> 1;                      /* local node, 2 halves/node */            \
  int node = b * 128 + t;

__global__ __launch_bounds__(256) void k_agg_relu_bf(
    const unsigned short* __restrict__ p, const float* __restrict__ dinv,
    const int* __restrict__ bucket_st, const unsigned* __restrict__ binned,
    const float* __restrict__ bias, unsigned short* __restrict__ h, int n) {
  AGG_PUSH_BODY
  if (node < n) {
    float di = dinv[node];
    uint4 q = *(const uint4*)(psl + (unsigned)node * 8u + (unsigned)half * 4u);
    const float* a = &accs[t * ASTR + half * 8];
    const float* bb = bias + slice * 16 + half * 8;
    float r0 = fmaxf((a[0] + bflo(q.x)) * di + bb[0], 0.f);
    float r1 = fmaxf((a[1] + bfhi(q.x)) * di + bb[1], 0.f);
    float r2 = fmaxf((a[2] + bflo(q.y)) * di + bb[2], 0.f);
    float r3 = fmaxf((a[3] + bfhi(q.y)) * di + bb[3], 0.f);
    float r4 = fmaxf((a[4] + bflo(q.z)) * di + bb[4], 0.f);
    float r5 = fmaxf((a[5] + bfhi(q.z)) * di + bb[5], 0.f);
    float r6 = fmaxf((a[6] + bflo(q.w)) * di + bb[6], 0.f);
    float r7 = fmaxf((a[7] + bfhi(q.w)) * di + bb[7], 0.f);
    uint4 u;
    u.x = (unsigned)f2bf(r0) | ((unsigned)f2bf(r1) << 16);
    u.y = (unsigned)f2bf(r2) | ((unsigned)f2bf(r3) << 16);
    u.z = (unsigned)f2bf(r4) | ((unsigned)f2bf(r5) << 16);
    u.w = (unsigned)f2bf(r6) | ((unsigned)f2bf(r7) << 16);
    *(uint4*)((unsigned*)h + ((size_t)slice * (n + 1) + node) * 8 + half * 4) = u;
  }
}

__global__ __launch_bounds__(256) void k_agg_out_bf(
    const unsigned short* __restrict__ p, const float* __restrict__ dinv,
    const int* __restrict__ bucket_st, const unsigned* __restrict__ binned,
    const float* __restrict__ bmu, const float* __restrict__ blv,
    float* __restrict__ out, int n) {
  AGG_PUSH_BODY
  if (node < n) {
    float di = dinv[node];
    uint4 q = *(const uint4*)(psl + (unsigned)node * 8u + (unsigned)half * 4u);
    const float* a = &accs[t * ASTR + half * 8];
    // slices 0-3 -> mu channels [0,64); slices 4-7 -> lv channels [0,64)
    const float* bp = (slice < 4) ? (bmu + slice * 16 + half * 8)
                                  : (blv + (slice - 4) * 16 + half * 8);
    float* op = (slice < 4)
                    ? (out + (size_t)node * C_OUT + slice * 16 + half * 8)
                    : (out + (size_t)(n + node) * C_OUT + (slice - 4) * 16 + half * 8);
    float4 o0 = {(a[0] + bflo(q.x)) * di + bp[0], (a[1] + bfhi(q.x)) * di + bp[1],
                 (a[2] + bflo(q.y)) * di + bp[2], (a[3] + bfhi(q.y)) * di + bp[3]};
    float4 o1 = {(a[4] + bflo(q.z)) * di + bp[4], (a[5] + bfhi(q.z)) * di + bp[5],
                 (a[6] + bflo(q.w)) * di + bp[6], (a[7] + bfhi(q.w)) * di + bp[7]};
    *(float4*)op = o0;
    *(float4*)(op + 4) = o1;
  }
}

// ---------------------------------------------------------------------------
extern "C" void kernel_launch(void* const* d_in, const int* in_sizes, int n_in,
                              void* d_out, int out_size, void* d_ws, size_t ws_size,
                              hipStream_t stream) {
  const float* x   = (const float*)d_in[0];
  const int*   ei  = (const int*)d_in[1];   // int32 on the wire (JAX x64 off)
  const float* W1  = (const float*)d_in[2];
  const float* b1  = (const float*)d_in[3];
  const float* Wmu = (const float*)d_in[4];
  const float* bmu = (const float*)d_in[5];
  const float* Wlv = (const float*)d_in[6];
  const float* blv = (const float*)d_in[7];
  float* out = (float*)d_out;

  const int n = in_sizes[0] / C_IN;
  const int E = in_sizes[1] / 2;
  const int* src = ei;
  const int* dst = ei + E;

  char* w = (char*)d_ws;
  auto alloc = [&](size_t bytes) -> void* {
    void* pp = (void*)w;
    w += (bytes + 255) & ~(size_t)255;
    return pp;
  };
  float*          dinv       = (float*)alloc((size_t)n * 4);
  int*            histmat    = (int*)alloc((size_t)P1WGS * NBUCK * 4);
  int*            bucket_tot = (int*)alloc((size_t)NBUCK * 4);
  int*            bucket_st  = (int*)alloc((size_t)(NBUCK + 1) * 4);
  unsigned*       binned     = (unsigned*)alloc((size_t)E * 4);
  unsigned short* bswz1      = (unsigned short*)alloc((size_t)C_IN * 128 * 2);
  unsigned short* bswz2      = (unsigned short*)alloc((size_t)HID * 128 * 2);
  unsigned short* p1         = (unsigned short*)alloc((size_t)(n + 1) * 128 * 2);
  unsigned short* hbuf       = (unsigned short*)alloc((size_t)(n + 1) * 128 * 2);
  unsigned short* p2         = (unsigned short*)alloc((size_t)(n + 1) * 128 * 2);
  (void)ws_size; (void)n_in; (void)out_size;

  const int TB = 256;
  const int rows = n + 1;
  const int gemm_bks = (n + 63) / 64;
  const int nbk = (n + 127) / 128;            // buckets w/ valid nodes
  const int agg_bks = nbk * 8;                // (bucket, slice) pairs

  // ---- CSR build: LDS radix binning, no global atomics ----
  k_bin_count<<<P1WGS, TB, 0, stream>>>(dst, histmat, E);
  k_col_scan<<<NBUCK, TB, 0, stream>>>(histmat, bucket_tot);
  k_bucket_scan<<<1, NBUCK, 0, stream>>>(bucket_tot, bucket_st, E);
  k_bin_scatter<<<P1WGS, TB, 0, stream>>>(src, dst, histmat, bucket_st, binned, E);
  k_bucket_deg<<<nbk, TB, 0, stream>>>(binned, bucket_st, dinv, n);

  // ---- weight pre-swizzle ----
  k_prep<<<24, 256, 0, stream>>>(W1, Wmu, Wlv, bswz1, bswz2);

  // ---- layer 1 ----
  k_gemm_mfma<float, C_IN><<<gemm_bks, TB, 0, stream>>>(x, bswz1, p1, dinv, n, rows);
  k_agg_relu_bf<<<agg_bks, TB, 0, stream>>>(p1, dinv, bucket_st, binned, b1, hbuf, n);

  // ---- layer 2+3 fused ----
  k_gemm_mfma<unsigned short, HID><<<gemm_bks, TB, 0, stream>>>(hbuf, bswz2, p2, dinv, n, rows);
  k_agg_out_bf<<<agg_bks, TB, 0, stream>>>(p2, dinv, bucket_st, binned, bmu, blv, out, n);
}

// Round 6
// 460.967 us; speedup vs baseline: 5.1326x; 5.1326x over previous
//
#include <hip/hip_runtime.h>

// ---------------------------------------------------------------------------
// GCN encoder, bf16 staging + MFMA GEMMs + XCD-sliced padded-CSR pull agg.
//   h  = relu(Agg(x@W1) + b1);  [mu|lv] = Agg(h@[Wmu|Wlv]) + bias
// Agg(p)[i] = dinv[i] * ( sum_{e: dst=i} p'[src] + p'[i] ), p' = p*dinv[row]
// dinv[src] folded into GEMM epilogue.
// Staged activations SLICE-MAJOR: p[slice][rows][16ch] (16 bf16 = 32B),
// rows = n+1, row n zeroed. Slice s handled only by WGs with bid%8==s ->
// XCD s (round-robin dispatch); per-XCD working set = contiguous 3.2MB
// < 4MiB L2 (R4-verified: FETCH 661->81MB).
// Agg execution (R4 was bpermute-latency-bound, R5 LDS-atomic-serialized):
// padded CSR pull. Rows padded to x4 with index n. 4 lanes/node; per step
// one shared-address uint4 csr load (HW broadcast) + 4 independent dwordx2
// row loads + straight-line adds. No LDS, no atomics, no cross-lane ops.
// CSR build: LDS radix binning (bucket = dst>>7), zero global atomics.
// Requires n <= 131072 (n = 100000 here).
// ---------------------------------------------------------------------------

#define C_IN  256
#define HID   128
#define C_OUT 64
#define NBUCK 1024
#define P1WGS 256

typedef __attribute__((ext_vector_type(8))) short bf16x8;
typedef __attribute__((ext_vector_type(4))) float f32x4;

__device__ inline unsigned short f2bf(float f) {  // round-to-nearest-even
  unsigned u = __float_as_uint(f);
  unsigned r = u + 0x7FFF + ((u >> 16) & 1);
  return (unsigned short)(r >> 16);
}
__device__ inline float bflo(unsigned v) { return __uint_as_float(v << 16); }
__device__ inline float bfhi(unsigned v) { return __uint_as_float(v & 0xFFFF0000u); }

// ---------------- P1: per-WG bucket histogram (LDS atomics only) -------------
__global__ __launch_bounds__(256) void k_bin_count(const int* __restrict__ dst,
                                                   int* __restrict__ histmat, int E) {
  __shared__ int h[NBUCK];
  int tid = threadIdx.x;
  for (int i = tid; i < NBUCK; i += 256) h[i] = 0;
  __syncthreads();
  for (int e = blockIdx.x * 256 + tid; e < E; e += P1WGS * 256)
    atomicAdd(&h[dst[e] >> 7], 1);
  __syncthreads();
  for (int i = tid; i < NBUCK; i += 256)
    histmat[blockIdx.x * NBUCK + i] = h[i];
}

// ---------------- P2: per-bucket exclusive scan across WGs (in place) --------
__global__ __launch_bounds__(256) void k_col_scan(int* __restrict__ histmat,
                                                  int* __restrict__ bucket_tot) {
  __shared__ int sh[P1WGS];
  int b = blockIdx.x;
  int t = threadIdx.x;
  int v = histmat[t * NBUCK + b];
  sh[t] = v; __syncthreads();
  for (int ofs = 1; ofs < P1WGS; ofs <<= 1) {
    int add = (t >= ofs) ? sh[t - ofs] : 0;
    __syncthreads();
    sh[t] += add;
    __syncthreads();
  }
  histmat[t * NBUCK + b] = sh[t] - v;  // exclusive
  if (t == P1WGS - 1) bucket_tot[b] = sh[t];
}

// ---------------- P3: generic exclusive scan over NBUCK totals ---------------
__global__ void k_scan(const int* __restrict__ tot, int* __restrict__ startv) {
  __shared__ int sh[NBUCK];
  int t = threadIdx.x;
  int v = tot[t];
  sh[t] = v; __syncthreads();
  for (int ofs = 1; ofs < NBUCK; ofs <<= 1) {
    int add = (t >= ofs) ? sh[t - ofs] : 0;
    __syncthreads();
    sh[t] += add;
    __syncthreads();
  }
  startv[t] = sh[t] - v;
  if (t == NBUCK - 1) startv[NBUCK] = sh[t];
}

// ---------------- P4: scatter edges into bucket-segmented array --------------
__global__ __launch_bounds__(256) void k_bin_scatter(const int* __restrict__ src,
                                                     const int* __restrict__ dst,
                                                     const int* __restrict__ histmat,
                                                     const int* __restrict__ bucket_start,
                                                     unsigned* __restrict__ binned, int E) {
  __shared__ int cur[NBUCK];
  int tid = threadIdx.x;
  for (int i = tid; i < NBUCK; i += 256)
    cur[i] = bucket_start[i] + histmat[blockIdx.x * NBUCK + i];
  __syncthreads();
  for (int e = blockIdx.x * 256 + tid; e < E; e += P1WGS * 256) {
    int d = dst[e];
    int pos = atomicAdd(&cur[d >> 7], 1);
    binned[pos] = (unsigned)src[e] | ((unsigned)(d & 127) << 17);
  }
}

// ---------------- P5: per-bucket deg/dinv + padded-size scan -----------------
// prow_start[node] <- LOCAL padded offset within bucket; pbtot[b] <- padded tot
__global__ __launch_bounds__(256) void k_bucket_deg(const unsigned* __restrict__ binned,
                                                    const int* __restrict__ bucket_st,
                                                    float* __restrict__ dinv,
                                                    int* __restrict__ prow_start,
                                                    int* __restrict__ pbtot, int n) {
  __shared__ int h[128], ls[128];
  int b = blockIdx.x, t = threadIdx.x;
  int start = bucket_st[b], end = bucket_st[b + 1];
  if (t < 128) h[t] = 0;
  __syncthreads();
  for (int e = start + t; e < end; e += 256)
    atomicAdd(&h[binned[e] >> 17], 1);
  __syncthreads();
  int pd = 0;
  if (t < 128) { pd = (h[t] + 3) & ~3; ls[t] = pd; }
  __syncthreads();
  for (int ofs = 1; ofs < 128; ofs <<= 1) {
    int add = (t < 128 && t >= ofs) ? ls[t - ofs] : 0;
    __syncthreads();
    if (t < 128) ls[t] += add;
    __syncthreads();
  }
  if (t < 128) {
    int node = b * 128 + t;
    if (node < n) {
      dinv[node] = rsqrtf((float)h[t] + 1.0f);
      prow_start[node] = ls[t] - pd;   // local exclusive offset
    }
    if (t == 127) pbtot[b] = ls[127];
  }
}

// ---------------- P6: fill padded CSR (globalize offsets, scatter, pad) ------
__global__ __launch_bounds__(256) void k_csr_fill(const unsigned* __restrict__ binned,
                                                  const int* __restrict__ bucket_st,
                                                  const int* __restrict__ pbstart,
                                                  int* __restrict__ prow_start,
                                                  int* __restrict__ csr, int n) {
  __shared__ int c[128];
  int b = blockIdx.x, t = threadIdx.x;
  int start = bucket_st[b], end = bucket_st[b + 1];
  int pbs = pbstart[b];
  int node = b * 128 + t;
  if (t < 128 && node < n) {
    int g = pbs + prow_start[node];
    prow_start[node] = g;              // globalize in place
    c[t] = g;
  }
  if (b == 0 && t == 0) prow_start[n] = pbstart[NBUCK];
  __syncthreads();
  for (int e = start + t; e < end; e += 256) {
    unsigned v = binned[e];
    int pos = atomicAdd(&c[v >> 17], 1);
    csr[pos] = (int)(v & 0x1FFFF);
  }
  __syncthreads();
  if (t < 128 && node < n) {
    int cur = c[t];
    while (cur & 3) csr[cur++] = n;    // pad to x4 with zero-row index
  }
}

// ---------------- weight pre-swizzle + zero-row init -------------------------
// Bswz[s][t][L][j] = bf16( B[s*32 + (L>>4)*8 + j][t*16 + (L&15)] )
__global__ void k_prep(const float* __restrict__ W1, const float* __restrict__ Wmu,
                       const float* __restrict__ Wlv,
                       unsigned short* __restrict__ bswz1,
                       unsigned short* __restrict__ bswz2,
                       unsigned* __restrict__ p1d, unsigned* __restrict__ p2d,
                       int rows) {  // rows = n+1; zero row rows-1 of each slice
  int idx = blockIdx.x * 256 + threadIdx.x;
  if (idx < 4096) {            // W1: (256/32)*8*64
    int L = idx & 63, t = (idx >> 6) & 7, s = idx >> 9;
    const float* srcp = W1 + (size_t)(s * 32 + ((L >> 4) << 3)) * 128 + t * 16 + (L & 15);
    unsigned short* dstp = bswz1 + (size_t)idx * 8;
#pragma unroll
    for (int j = 0; j < 8; j++) dstp[j] = f2bf(srcp[(size_t)j * 128]);
  } else if (idx < 6144) {     // [Wmu|Wlv]: (128/32)*8*64
    int id2 = idx - 4096;
    int L = id2 & 63, t = (id2 >> 6) & 7, s = id2 >> 9;
    int nn = t * 16 + (L & 15);
    int k0 = s * 32 + ((L >> 4) << 3);
    const float* W = (nn < C_OUT) ? (Wmu + nn) : (Wlv + (nn - C_OUT));
    unsigned short* dstp = bswz2 + (size_t)id2 * 8;
#pragma unroll
    for (int j = 0; j < 8; j++) dstp[j] = f2bf(W[(size_t)(k0 + j) * C_OUT]);
  } else if (idx < 6208) {     // zero row (rows-1) of each of 8 slices, p1
    int j = idx - 6144;        // 8 slices x 8 dwords
    p1d[((size_t)(j >> 3) * rows + (rows - 1)) * 8 + (j & 7)] = 0u;
  } else if (idx < 6272) {     // same for p2
    int j = idx - 6208;
    p2d[((size_t)(j >> 3) * rows + (rows - 1)) * 8 + (j & 7)] = 0u;
  }
}

// -------- MFMA GEMM: C[slice][row][16](bf16) = (A @ B) * dinv[row] -----------
// A: float row-major [M][K] (layer 1) or bf16 slice-major [K/16][rows][16]
// (layer 2). C always slice-major with row stride `rows`.
template <typename AT, int K>
__global__ __launch_bounds__(256) void k_gemm_mfma(const AT* __restrict__ A,
                                                   const unsigned short* __restrict__ bswz,
                                                   unsigned short* __restrict__ C,
                                                   const float* __restrict__ dinv,
                                                   int M, int rows) {
  constexpr int NS = K / 32;
  int wave = threadIdx.x >> 6, lane = threadIdx.x & 63;
  int m0 = blockIdx.x * 64 + wave * 16;
  int lrow = lane & 15, lq = lane >> 4;
  int arow = m0 + lrow;
  bool rv = arow < M;
  int arow_c = rv ? arow : 0;

  auto loadA = [&](int s) -> bf16x8 {
    if (sizeof(AT) == 4) {     // row-major f32
      const float* af = (const float*)A + (size_t)arow_c * K + lq * 8 + s * 32;
      float4 u0 = rv ? *(const float4*)(af) : float4{0, 0, 0, 0};
      float4 u1 = rv ? *(const float4*)(af + 4) : float4{0, 0, 0, 0};
      union { unsigned short us[8]; bf16x8 v; } tmp;
      tmp.us[0] = f2bf(u0.x); tmp.us[1] = f2bf(u0.y);
      tmp.us[2] = f2bf(u0.z); tmp.us[3] = f2bf(u0.w);
      tmp.us[4] = f2bf(u1.x); tmp.us[5] = f2bf(u1.y);
      tmp.us[6] = f2bf(u1.z); tmp.us[7] = f2bf(u1.w);
      return tmp.v;
    } else {                   // bf16 slice-major: channels c0..c0+7, c0%16 in {0,8}
      int c0 = lq * 8 + s * 32;
      const unsigned short* ab = (const unsigned short*)A +
          ((size_t)(c0 >> 4) * rows + arow_c) * 16 + (c0 & 15);
      return rv ? *(const bf16x8*)(ab) : (bf16x8)(short)0;
    }
  };

  f32x4 acc[8];
#pragma unroll
  for (int t = 0; t < 8; t++) acc[t] = (f32x4){0.f, 0.f, 0.f, 0.f};

  bf16x8 a_cur = loadA(0);
  bf16x8 b_cur[8];
#pragma unroll
  for (int t = 0; t < 8; t++)
    b_cur[t] = *(const bf16x8*)(bswz + lane * 8 + t * 512);

#pragma unroll
  for (int s = 0; s < NS; ++s) {
    bf16x8 a_nxt = a_cur;
    bf16x8 b_nxt[8];
    if (s + 1 < NS) {
      a_nxt = loadA(s + 1);
      const unsigned short* bp = bswz + (size_t)(s + 1) * 4096 + lane * 8;
#pragma unroll
      for (int t = 0; t < 8; t++) b_nxt[t] = *(const bf16x8*)(bp + t * 512);
    }
#pragma unroll
    for (int t = 0; t < 8; t++)
      acc[t] = __builtin_amdgcn_mfma_f32_16x16x32_bf16(a_cur, b_cur[t], acc[t], 0, 0, 0);
    a_cur = a_nxt;
    if (s + 1 < NS) {
#pragma unroll
      for (int t = 0; t < 8; t++) b_cur[t] = b_nxt[t];
    }
  }
#pragma unroll
  for (int i = 0; i < 4; i++) {
    int rr = m0 + lq * 4 + i;
    if (rr < M) {
      float dsc = dinv[rr];           // fold dinv[src] into staged rows
#pragma unroll
      for (int t = 0; t < 8; t++)     // channel t*16+lrow -> slice t, pos lrow
        C[((size_t)t * rows + rr) * 16 + lrow] = f2bf(acc[t][i] * dsc);
    }
  }
}

// ---------------- agg: padded-CSR pull, 4 lanes/node, no LDS -----------------
// Per 4-edge step: one shared-address uint4 csr load (HW broadcast across the
// 4 lanes) + 4 independent dwordx2 slice-row loads + straight-line adds.
#define AGG_PULL_BODY                                                               \
  int tid = threadIdx.x;                                                            \
  int slice = blockIdx.x & 7;            /* slice == XCD (round-robin) */           \
  int blk = blockIdx.x >> 3;                                                        \
  int node = blk * 64 + (tid >> 2);      /* 64 nodes/WG, 16/wave */                 \
  int li = tid & 3;                      /* 4 lanes/node, 4 ch each */              \
  bool valid = node < n;                                                            \
  int rs = 0, re = 0;                                                               \
  if (valid) { rs = prow_start[node]; re = prow_start[node + 1]; }                  \
  const unsigned* psl = (const unsigned*)p + (size_t)slice * (size_t)(n + 1) * 8;   \
  float a0 = 0.f, a1 = 0.f, a2 = 0.f, a3 = 0.f;                                     \
  for (int e = rs; e < re; e += 4) {                                                \
    uint4 se = *(const uint4*)(csr + e);                                            \
    uint2 q0 = *(const uint2*)(psl + (unsigned)se.x * 8u + li * 2);                 \
    uint2 q1 = *(const uint2*)(psl + (unsigned)se.y * 8u + li * 2);                 \
    uint2 q2 = *(const uint2*)(psl + (unsigned)se.z * 8u + li * 2);                 \
    uint2 q3 = *(const uint2*)(psl + (unsigned)se.w * 8u + li * 2);                 \
    a0 += bflo(q0.x); a1 += bfhi(q0.x); a2 += bflo(q0.y); a3 += bfhi(q0.y);         \
    a0 += bflo(q1.x); a1 += bfhi(q1.x); a2 += bflo(q1.y); a3 += bfhi(q1.y);         \
    a0 += bflo(q2.x); a1 += bfhi(q2.x); a2 += bflo(q2.y); a3 += bfhi(q2.y);         \
    a0 += bflo(q3.x); a1 += bfhi(q3.x); a2 += bflo(q3.y); a3 += bfhi(q3.y);         \
  }

__global__ __launch_bounds__(256) void k_agg_relu_bf(
    const unsigned short* __restrict__ p, const float* __restrict__ dinv,
    const int* __restrict__ prow_start, const int* __restrict__ csr,
    const float* __restrict__ bias, unsigned short* __restrict__ h, int n) {
  AGG_PULL_BODY
  if (valid) {
    float di = dinv[node];
    uint2 q = *(const uint2*)(psl + (unsigned)node * 8u + li * 2);  // self edge
    const float* bb = bias + slice * 16 + li * 4;
    float r0 = fmaxf((a0 + bflo(q.x)) * di + bb[0], 0.f);
    float r1 = fmaxf((a1 + bfhi(q.x)) * di + bb[1], 0.f);
    float r2 = fmaxf((a2 + bflo(q.y)) * di + bb[2], 0.f);
    float r3 = fmaxf((a3 + bfhi(q.y)) * di + bb[3], 0.f);
    uint2 u;
    u.x = (unsigned)f2bf(r0) | ((unsigned)f2bf(r1) << 16);
    u.y = (unsigned)f2bf(r2) | ((unsigned)f2bf(r3) << 16);
    *(uint2*)((unsigned*)h + ((size_t)slice * (n + 1) + node) * 8 + li * 2) = u;
  }
}

__global__ __launch_bounds__(256) void k_agg_out_bf(
    const unsigned short* __restrict__ p, const float* __restrict__ dinv,
    const int* __restrict__ prow_start, const int* __restrict__ csr,
    const float* __restrict__ bmu, const float* __restrict__ blv,
    float* __restrict__ out, int n) {
  AGG_PULL_BODY
  if (valid) {
    float di = dinv[node];
    uint2 q = *(const uint2*)(psl + (unsigned)node * 8u + li * 2);  // self edge
    // slices 0-3 -> mu channels [0,64); slices 4-7 -> lv channels [0,64)
    const float* bp = (slice < 4) ? (bmu + slice * 16 + li * 4)
                                  : (blv + (slice - 4) * 16 + li * 4);
    float* op = (slice < 4)
                    ? (out + (size_t)node * C_OUT + slice * 16 + li * 4)
                    : (out + (size_t)(n + node) * C_OUT + (slice - 4) * 16 + li * 4);
    float4 o = {(a0 + bflo(q.x)) * di + bp[0], (a1 + bfhi(q.x)) * di + bp[1],
                (a2 + bflo(q.y)) * di + bp[2], (a3 + bfhi(q.y)) * di + bp[3]};
    *(float4*)op = o;
  }
}

// ---------------------------------------------------------------------------
extern "C" void kernel_launch(void* const* d_in, const int* in_sizes, int n_in,
                              void* d_out, int out_size, void* d_ws, size_t ws_size,
                              hipStream_t stream) {
  const float* x   = (const float*)d_in[0];
  const int*   ei  = (const int*)d_in[1];   // int32 on the wire (JAX x64 off)
  const float* W1  = (const float*)d_in[2];
  const float* b1  = (const float*)d_in[3];
  const float* Wmu = (const float*)d_in[4];
  const float* bmu = (const float*)d_in[5];
  const float* Wlv = (const float*)d_in[6];
  const float* blv = (const float*)d_in[7];
  float* out = (float*)d_out;

  const int n = in_sizes[0] / C_IN;
  const int E = in_sizes[1] / 2;
  const int* src = ei;
  const int* dst = ei + E;

  char* w = (char*)d_ws;
  auto alloc = [&](size_t bytes) -> void* {
    void* pp = (void*)w;
    w += (bytes + 255) & ~(size_t)255;
    return pp;
  };
  float*          dinv       = (float*)alloc((size_t)n * 4);
  int*            histmat    = (int*)alloc((size_t)P1WGS * NBUCK * 4);
  int*            bucket_tot = (int*)alloc((size_t)NBUCK * 4);
  int*            bucket_st  = (int*)alloc((size_t)(NBUCK + 1) * 4);
  int*            pbtot      = (int*)alloc((size_t)NBUCK * 4);
  int*            pbstart    = (int*)alloc((size_t)(NBUCK + 1) * 4);
  unsigned*       binned     = (unsigned*)alloc((size_t)E * 4);
  int*            prow_start = (int*)alloc((size_t)(n + 1) * 4);
  int*            csr        = (int*)alloc(((size_t)E + 3 * n + 16) * 4);
  unsigned short* bswz1      = (unsigned short*)alloc((size_t)C_IN * 128 * 2);
  unsigned short* bswz2      = (unsigned short*)alloc((size_t)HID * 128 * 2);
  unsigned short* p1         = (unsigned short*)alloc((size_t)(n + 1) * 128 * 2);
  unsigned short* hbuf       = (unsigned short*)alloc((size_t)(n + 1) * 128 * 2);
  unsigned short* p2         = (unsigned short*)alloc((size_t)(n + 1) * 128 * 2);
  (void)ws_size; (void)n_in; (void)out_size;

  const int TB = 256;
  const int rows = n + 1;
  const int gemm_bks = (n + 63) / 64;
  const int nbk = (n + 127) / 128;            // buckets w/ valid nodes
  const int agg_bks = ((n + 63) / 64) * 8;    // 64 nodes/WG x 8 slices

  // ---- padded-CSR build: LDS radix binning, no global atomics ----
  k_bin_count<<<P1WGS, TB, 0, stream>>>(dst, histmat, E);
  k_col_scan<<<NBUCK, TB, 0, stream>>>(histmat, bucket_tot);
  k_scan<<<1, NBUCK, 0, stream>>>(bucket_tot, bucket_st);
  k_bin_scatter<<<P1WGS, TB, 0, stream>>>(src, dst, histmat, bucket_st, binned, E);
  k_bucket_deg<<<NBUCK, TB, 0, stream>>>(binned, bucket_st, dinv, prow_start, pbtot, n);
  k_scan<<<1, NBUCK, 0, stream>>>(pbtot, pbstart);
  k_csr_fill<<<nbk, TB, 0, stream>>>(binned, bucket_st, pbstart, prow_start, csr, n);

  // ---- weight pre-swizzle + zero row (rows-1) of every slice of p1/p2 ----
  k_prep<<<25, 256, 0, stream>>>(W1, Wmu, Wlv, bswz1, bswz2,
                                 (unsigned*)p1, (unsigned*)p2, rows);

  // ---- layer 1 ----
  k_gemm_mfma<float, C_IN><<<gemm_bks, TB, 0, stream>>>(x, bswz1, p1, dinv, n, rows);
  k_agg_relu_bf<<<agg_bks, TB, 0, stream>>>(p1, dinv, prow_start, csr, b1, hbuf, n);

  // ---- layer 2+3 fused ----
  k_gemm_mfma<unsigned short, HID><<<gemm_bks, TB, 0, stream>>>(hbuf, bswz2, p2, dinv, n, rows);
  k_agg_out_bf<<<agg_bks, TB, 0, stream>>>(p2, dinv, prow_start, csr, bmu, blv, out, n);
}

// Round 7
// 402.876 us; speedup vs baseline: 5.8727x; 1.1442x over previous
//
#include <hip/hip_runtime.h>

// ---------------------------------------------------------------------------
// GCN encoder, bf16 staging + MFMA GEMMs + bpermute-broadcast gather agg.
//   h  = relu(Agg(x@W1) + b1);  [mu|lv] = Agg(h@[Wmu|Wlv]) + bias
// Agg(p)[i] = dinv[i] * ( sum_{e: dst=i} p'[src] + p'[i] ), p' = p*dinv[row]
// dinv[src] folded into GEMM epilogue (p' = bf16(acc*dinv)).
// Agg: 4 nodes/wave, 16 lanes x 8ch dwordx4 (full 256B row per instr —
// R4/R6 proved narrower access granularity loses 2.3x line rate), bpermute
// broadcast, idle slots read zeroed row n. R7 delta vs R1: 16-deep load
// batching — all 16 bpermutes, then 16 independent uint4 loads, then
// accumulate; raises outstanding misses/wave ~4x to attack latency-bound
// line rate (R1: 23 Glines/s at 22% VALU, far under TA/BW ceilings).
// CSR build: LDS radix binning (bucket = dst>>7), zero global atomics.
// Requires n <= 131072 (n = 100000 here).
// ---------------------------------------------------------------------------

#define C_IN  256
#define HID   128
#define C_OUT 64
#define NBUCK 1024
#define P1WGS 256

typedef __attribute__((ext_vector_type(8))) short bf16x8;
typedef __attribute__((ext_vector_type(4))) float f32x4;

__device__ inline unsigned short f2bf(float f) {  // round-to-nearest-even
  unsigned u = __float_as_uint(f);
  unsigned r = u + 0x7FFF + ((u >> 16) & 1);
  return (unsigned short)(r >> 16);
}
__device__ inline float bflo(unsigned v) { return __uint_as_float(v << 16); }
__device__ inline float bfhi(unsigned v) { return __uint_as_float(v & 0xFFFF0000u); }

// ---------------- P1: per-WG bucket histogram (LDS atomics only) -------------
__global__ __launch_bounds__(256) void k_bin_count(const int* __restrict__ dst,
                                                   int* __restrict__ histmat, int E) {
  __shared__ int h[NBUCK];
  int tid = threadIdx.x;
  for (int i = tid; i < NBUCK; i += 256) h[i] = 0;
  __syncthreads();
  for (int e = blockIdx.x * 256 + tid; e < E; e += P1WGS * 256)
    atomicAdd(&h[dst[e] >> 7], 1);
  __syncthreads();
  for (int i = tid; i < NBUCK; i += 256)
    histmat[blockIdx.x * NBUCK + i] = h[i];
}

// ---------------- P2: per-bucket exclusive scan across WGs (in place) --------
__global__ __launch_bounds__(256) void k_col_scan(int* __restrict__ histmat,
                                                  int* __restrict__ bucket_tot) {
  __shared__ int sh[P1WGS];
  int b = blockIdx.x;
  int t = threadIdx.x;
  int v = histmat[t * NBUCK + b];
  sh[t] = v; __syncthreads();
  for (int ofs = 1; ofs < P1WGS; ofs <<= 1) {
    int add = (t >= ofs) ? sh[t - ofs] : 0;
    __syncthreads();
    sh[t] += add;
    __syncthreads();
  }
  histmat[t * NBUCK + b] = sh[t] - v;  // exclusive
  if (t == P1WGS - 1) bucket_tot[b] = sh[t];
}

// ---------------- P3: bucket_start = exclusive scan of bucket_tot ------------
__global__ void k_bucket_scan(const int* __restrict__ bucket_tot,
                              int* __restrict__ bucket_start, int E) {
  __shared__ int sh[NBUCK];
  int t = threadIdx.x;
  int v = bucket_tot[t];
  sh[t] = v; __syncthreads();
  for (int ofs = 1; ofs < NBUCK; ofs <<= 1) {
    int add = (t >= ofs) ? sh[t - ofs] : 0;
    __syncthreads();
    sh[t] += add;
    __syncthreads();
  }
  bucket_start[t] = sh[t] - v;
  if (t == NBUCK - 1) bucket_start[NBUCK] = E;
}

// ---------------- P4: scatter edges into bucket-segmented array --------------
__global__ __launch_bounds__(256) void k_bin_scatter(const int* __restrict__ src,
                                                     const int* __restrict__ dst,
                                                     const int* __restrict__ histmat,
                                                     const int* __restrict__ bucket_start,
                                                     unsigned* __restrict__ binned, int E) {
  __shared__ int cur[NBUCK];
  int tid = threadIdx.x;
  for (int i = tid; i < NBUCK; i += 256)
    cur[i] = bucket_start[i] + histmat[blockIdx.x * NBUCK + i];
  __syncthreads();
  for (int e = blockIdx.x * 256 + tid; e < E; e += P1WGS * 256) {
    int d = dst[e];
    int pos = atomicAdd(&cur[d >> 7], 1);
    binned[pos] = (unsigned)src[e] | ((unsigned)(d & 127) << 17);
  }
}

// ---------------- P5: per-bucket deg/dinv/row_start + CSR fill ---------------
__global__ __launch_bounds__(256) void k_bucket_csr(const unsigned* __restrict__ binned,
                                                    const int* __restrict__ bucket_start,
                                                    int* __restrict__ row_start,
                                                    float* __restrict__ dinv,
                                                    int* __restrict__ csr_src,
                                                    int n, int E) {
  __shared__ int h[128], ls[128], c[128];
  int b = blockIdx.x, t = threadIdx.x;
  int start = bucket_start[b], end = bucket_start[b + 1];
  if (t < 128) h[t] = 0;
  __syncthreads();
  for (int e = start + t; e < end; e += 256)
    atomicAdd(&h[binned[e] >> 17], 1);
  __syncthreads();
  if (t < 128) ls[t] = h[t];
  __syncthreads();
  for (int ofs = 1; ofs < 128; ofs <<= 1) {
    int add = (t < 128 && t >= ofs) ? ls[t - ofs] : 0;
    __syncthreads();
    if (t < 128) ls[t] += add;
    __syncthreads();
  }
  if (t < 128) {
    int excl = ls[t] - h[t];
    ls[t] = excl;
    c[t] = excl;
    int node = b * 128 + t;
    if (node < n) {
      row_start[node] = start + excl;
      dinv[node] = rsqrtf((float)h[t] + 1.0f);
    }
  }
  if (b == 0 && t == 0) row_start[n] = E;
  __syncthreads();
  for (int e = start + t; e < end; e += 256) {
    unsigned v = binned[e];
    int pos = start + atomicAdd(&c[v >> 17], 1);
    csr_src[pos] = (int)(v & 0x1FFFF);
  }
}

// ---------------- weight pre-swizzle + zero-row init -------------------------
// Bswz[s][t][L][j] = bf16( B[s*32 + (L>>4)*8 + j][t*16 + (L&15)] )
__global__ void k_prep(const float* __restrict__ W1, const float* __restrict__ Wmu,
                       const float* __restrict__ Wlv,
                       unsigned short* __restrict__ bswz1,
                       unsigned short* __restrict__ bswz2,
                       unsigned* __restrict__ p1z, unsigned* __restrict__ p2z) {
  int idx = blockIdx.x * 256 + threadIdx.x;
  if (idx < 4096) {            // W1: (256/32)*8*64
    int L = idx & 63, t = (idx >> 6) & 7, s = idx >> 9;
    const float* srcp = W1 + (size_t)(s * 32 + ((L >> 4) << 3)) * 128 + t * 16 + (L & 15);
    unsigned short* dstp = bswz1 + (size_t)idx * 8;
#pragma unroll
    for (int j = 0; j < 8; j++) dstp[j] = f2bf(srcp[(size_t)j * 128]);
  } else if (idx < 6144) {     // [Wmu|Wlv]: (128/32)*8*64
    int id2 = idx - 4096;
    int L = id2 & 63, t = (id2 >> 6) & 7, s = id2 >> 9;
    int nn = t * 16 + (L & 15);
    int k0 = s * 32 + ((L >> 4) << 3);
    const float* W = (nn < C_OUT) ? (Wmu + nn) : (Wlv + (nn - C_OUT));
    unsigned short* dstp = bswz2 + (size_t)id2 * 8;
#pragma unroll
    for (int j = 0; j < 8; j++) dstp[j] = f2bf(W[(size_t)(k0 + j) * C_OUT]);
  } else if (idx < 6208) {     // zero row n of p1 (64 dwords)
    p1z[idx - 6144] = 0u;
  } else if (idx < 6272) {     // zero row n of p2
    p2z[idx - 6208] = 0u;
  }
}

// ---------------- MFMA GEMM: C[M,128](bf16) = (A[M,K] @ B[K,128]) * dinv[row] --
template <typename AT, int K>
__global__ __launch_bounds__(256) void k_gemm_mfma(const AT* __restrict__ A,
                                                   const unsigned short* __restrict__ bswz,
                                                   unsigned short* __restrict__ C,
                                                   const float* __restrict__ dinv,
                                                   int M) {
  constexpr int NS = K / 32;
  int wave = threadIdx.x >> 6, lane = threadIdx.x & 63;
  int m0 = blockIdx.x * 64 + wave * 16;
  int lrow = lane & 15, lq = lane >> 4;
  int arow = m0 + lrow;
  bool rv = arow < M;
  const AT* ap = A + (size_t)(rv ? arow : 0) * K + lq * 8;

  auto loadA = [&](int s) -> bf16x8 {
    if (sizeof(AT) == 4) {
      const float* af = (const float*)ap + s * 32;
      float4 u0 = rv ? *(const float4*)(af) : float4{0, 0, 0, 0};
      float4 u1 = rv ? *(const float4*)(af + 4) : float4{0, 0, 0, 0};
      union { unsigned short us[8]; bf16x8 v; } tmp;
      tmp.us[0] = f2bf(u0.x); tmp.us[1] = f2bf(u0.y);
      tmp.us[2] = f2bf(u0.z); tmp.us[3] = f2bf(u0.w);
      tmp.us[4] = f2bf(u1.x); tmp.us[5] = f2bf(u1.y);
      tmp.us[6] = f2bf(u1.z); tmp.us[7] = f2bf(u1.w);
      return tmp.v;
    } else {
      const unsigned short* ab = (const unsigned short*)ap + s * 32;
      return rv ? *(const bf16x8*)(ab) : (bf16x8)(short)0;
    }
  };

  f32x4 acc[8];
#pragma unroll
  for (int t = 0; t < 8; t++) acc[t] = (f32x4){0.f, 0.f, 0.f, 0.f};

  bf16x8 a_cur = loadA(0);
  bf16x8 b_cur[8];
#pragma unroll
  for (int t = 0; t < 8; t++)
    b_cur[t] = *(const bf16x8*)(bswz + lane * 8 + t * 512);

#pragma unroll
  for (int s = 0; s < NS; ++s) {
    bf16x8 a_nxt = a_cur;
    bf16x8 b_nxt[8];
    if (s + 1 < NS) {
      a_nxt = loadA(s + 1);
      const unsigned short* bp = bswz + (size_t)(s + 1) * 4096 + lane * 8;
#pragma unroll
      for (int t = 0; t < 8; t++) b_nxt[t] = *(const bf16x8*)(bp + t * 512);
    }
#pragma unroll
    for (int t = 0; t < 8; t++)
      acc[t] = __builtin_amdgcn_mfma_f32_16x16x32_bf16(a_cur, b_cur[t], acc[t], 0, 0, 0);
    a_cur = a_nxt;
    if (s + 1 < NS) {
#pragma unroll
      for (int t = 0; t < 8; t++) b_cur[t] = b_nxt[t];
    }
  }
#pragma unroll
  for (int i = 0; i < 4; i++) {
    int rr = m0 + lq * 4 + i;
    if (rr < M) {
      float dsc = dinv[rr];           // fold dinv[src] into staged rows
      unsigned short* cp = C + (size_t)rr * 128 + lrow;
#pragma unroll
      for (int t = 0; t < 8; t++) cp[t * 16] = f2bf(acc[t][i] * dsc);
    }
  }
}

// ---------------- gather aggregation: 4 nodes/wave, 16-deep batched ----------
// p has n+1 rows of 128 bf16 (256B); row n is all-zero (idle-slot target).
// Per 16-edge window: 16 bpermutes -> 16 independent uint4 loads -> adds.
// Static indices throughout (rule #20: no runtime-indexed reg arrays).
#define AGG_V4_BODY                                                                 \
  int tid = threadIdx.x;                                                            \
  int wid4 = blockIdx.x * 4 + (tid >> 6); /* 4 waves/WG */                          \
  int lane = tid & 63;                                                              \
  int li = lane & 15;                                                               \
  int node = (wid4 << 2) + (lane >> 4);                                             \
  int rs = 0, re = -1;                                                              \
  if (node < n) { rs = row_start[node]; re = row_start[node + 1]; }                 \
  int mc = re - rs + 1; /* edges incl. self */                                      \
  mc = max(mc, __shfl_xor(mc, 16, 64));                                             \
  mc = max(mc, __shfl_xor(mc, 32, 64));                                             \
  int maxcnt = __builtin_amdgcn_readfirstlane(mc);                                  \
  const char* pb = (const char*)p;                                                  \
  unsigned loff = (unsigned)(li << 4);                                              \
  int vb = (lane & 48) << 2; /* byte idx of group base lane for bpermute */         \
  float acc0 = 0.f, acc1 = 0.f, acc2 = 0.f, acc3 = 0.f;                             \
  float acc4 = 0.f, acc5 = 0.f, acc6 = 0.f, acc7 = 0.f;                             \
  for (int t0 = 0; t0 < maxcnt; t0 += 16) {                                         \
    int s = rs + t0 + li;                                                           \
    int sl = n; /* zero row */                                                      \
    if (s < re) sl = csr[s];                                                        \
    else if (s == re) sl = node; /* self edge */                                    \
    unsigned o[16];                                                                 \
    _Pragma("unroll")                                                               \
    for (int k = 0; k < 16; ++k)                                                    \
      o[k] = ((unsigned)__builtin_amdgcn_ds_bpermute(vb + (k << 2), sl)) << 8;      \
    uint4 v[16];                                                                    \
    _Pragma("unroll")                                                               \
    for (int k = 0; k < 16; ++k)                                                    \
      v[k] = *(const uint4*)(pb + (o[k] + loff));                                   \
    _Pragma("unroll")                                                               \
    for (int k = 0; k < 16; ++k) {                                                  \
      acc0 += bflo(v[k].x); acc1 += bfhi(v[k].x);                                   \
      acc2 += bflo(v[k].y); acc3 += bfhi(v[k].y);                                   \
      acc4 += bflo(v[k].z); acc5 += bfhi(v[k].z);                                   \
      acc6 += bflo(v[k].w); acc7 += bfhi(v[k].w);                                   \
    }                                                                               \
  }

__global__ __launch_bounds__(256) void k_agg_relu_bf(
    const unsigned short* __restrict__ p, const float* __restrict__ dinv,
    const int* __restrict__ row_start, const int* __restrict__ csr,
    const float* __restrict__ bias, unsigned short* __restrict__ h, int n) {
  AGG_V4_BODY
  if (node < n) {
    float di = dinv[node];
    float4 ba = *(const float4*)(bias + (li << 3));
    float4 bb = *(const float4*)(bias + (li << 3) + 4);
    float r0 = fmaxf(acc0 * di + ba.x, 0.f);
    float r1 = fmaxf(acc1 * di + ba.y, 0.f);
    float r2 = fmaxf(acc2 * di + ba.z, 0.f);
    float r3 = fmaxf(acc3 * di + ba.w, 0.f);
    float r4 = fmaxf(acc4 * di + bb.x, 0.f);
    float r5 = fmaxf(acc5 * di + bb.y, 0.f);
    float r6 = fmaxf(acc6 * di + bb.z, 0.f);
    float r7 = fmaxf(acc7 * di + bb.w, 0.f);
    uint4 u;
    u.x = (unsigned)f2bf(r0) | ((unsigned)f2bf(r1) << 16);
    u.y = (unsigned)f2bf(r2) | ((unsigned)f2bf(r3) << 16);
    u.z = (unsigned)f2bf(r4) | ((unsigned)f2bf(r5) << 16);
    u.w = (unsigned)f2bf(r6) | ((unsigned)f2bf(r7) << 16);
    *(uint4*)((char*)h + (((size_t)node) << 8) + loff) = u;
  }
}

__global__ __launch_bounds__(256) void k_agg_out_bf(
    const unsigned short* __restrict__ p, const float* __restrict__ dinv,
    const int* __restrict__ row_start, const int* __restrict__ csr,
    const float* __restrict__ bmu, const float* __restrict__ blv,
    float* __restrict__ out, int n) {
  AGG_V4_BODY
  if (node < n) {
    float di = dinv[node];
    const float* bp = (li < 8) ? (bmu + (li << 3)) : (blv + ((li - 8) << 3));
    float* op = (li < 8) ? (out + (size_t)node * C_OUT + (li << 3))
                         : (out + (size_t)(n + node) * C_OUT + ((li - 8) << 3));
    float4 b0 = *(const float4*)(bp);
    float4 b1 = *(const float4*)(bp + 4);
    float4 o0 = {acc0 * di + b0.x, acc1 * di + b0.y,
                 acc2 * di + b0.z, acc3 * di + b0.w};
    float4 o1 = {acc4 * di + b1.x, acc5 * di + b1.y,
                 acc6 * di + b1.z, acc7 * di + b1.w};
    *(float4*)op = o0;
    *(float4*)(op + 4) = o1;
  }
}

// ---------------------------------------------------------------------------
extern "C" void kernel_launch(void* const* d_in, const int* in_sizes, int n_in,
                              void* d_out, int out_size, void* d_ws, size_t ws_size,
                              hipStream_t stream) {
  const float* x   = (const float*)d_in[0];
  const int*   ei  = (const int*)d_in[1];   // int32 on the wire (JAX x64 off)
  const float* W1  = (const float*)d_in[2];
  const float* b1  = (const float*)d_in[3];
  const float* Wmu = (const float*)d_in[4];
  const float* bmu = (const float*)d_in[5];
  const float* Wlv = (const float*)d_in[6];
  const float* blv = (const float*)d_in[7];
  float* out = (float*)d_out;

  const int n = in_sizes[0] / C_IN;
  const int E = in_sizes[1] / 2;
  const int* src = ei;
  const int* dst = ei + E;

  char* w = (char*)d_ws;
  auto alloc = [&](size_t bytes) -> void* {
    void* pp = (void*)w;
    w += (bytes + 255) & ~(size_t)255;
    return pp;
  };
  float*          dinv       = (float*)alloc((size_t)n * 4);
  int*            row_start  = (int*)alloc((size_t)(n + 1) * 4);
  int*            histmat    = (int*)alloc((size_t)P1WGS * NBUCK * 4);
  int*            bucket_tot = (int*)alloc((size_t)NBUCK * 4);
  int*            bucket_st  = (int*)alloc((size_t)(NBUCK + 1) * 4);
  unsigned*       binned     = (unsigned*)alloc((size_t)E * 4);
  int*            csr_src    = (int*)alloc((size_t)E * 4);
  unsigned short* bswz1      = (unsigned short*)alloc((size_t)C_IN * 128 * 2);
  unsigned short* bswz2      = (unsigned short*)alloc((size_t)HID * 128 * 2);
  unsigned short* p1         = (unsigned short*)alloc((size_t)(n + 1) * 128 * 2);
  unsigned short* hbuf       = (unsigned short*)alloc((size_t)n * 128 * 2);
  unsigned short* p2         = (unsigned short*)alloc((size_t)(n + 1) * 128 * 2);
  (void)ws_size; (void)n_in; (void)out_size;

  const int TB = 256;
  const int gemm_bks = (n + 63) / 64;
  const int agg_bks = (n + 15) / 16;          // 4 nodes/wave, 4 waves/WG
  const int nbk_csr = (n + 127) / 128;        // buckets w/ valid nodes

  // ---- CSR build: LDS radix binning, no global atomics ----
  k_bin_count<<<P1WGS, TB, 0, stream>>>(dst, histmat, E);
  k_col_scan<<<NBUCK, TB, 0, stream>>>(histmat, bucket_tot);
  k_bucket_scan<<<1, NBUCK, 0, stream>>>(bucket_tot, bucket_st, E);
  k_bin_scatter<<<P1WGS, TB, 0, stream>>>(src, dst, histmat, bucket_st, binned, E);
  k_bucket_csr<<<nbk_csr, TB, 0, stream>>>(binned, bucket_st, row_start, dinv,
                                           csr_src, n, E);

  // ---- weight pre-swizzle + zero rows n of p1/p2 ----
  k_prep<<<25, 256, 0, stream>>>(W1, Wmu, Wlv, bswz1, bswz2,
                                 (unsigned*)(p1 + (size_t)n * 128),
                                 (unsigned*)(p2 + (size_t)n * 128));

  // ---- layer 1 ----
  k_gemm_mfma<float, C_IN><<<gemm_bks, TB, 0, stream>>>(x, bswz1, p1, dinv, n);
  k_agg_relu_bf<<<agg_bks, TB, 0, stream>>>(p1, dinv, row_start, csr_src, b1, hbuf, n);

  // ---- layer 2+3 fused ----
  k_gemm_mfma<unsigned short, HID><<<gemm_bks, TB, 0, stream>>>(hbuf, bswz2, p2, dinv, n);
  k_agg_out_bf<<<agg_bks, TB, 0, stream>>>(p2, dinv, row_start, csr_src, bmu, blv, out, n);
}

// Round 8
// 395.512 us; speedup vs baseline: 5.9820x; 1.0186x over previous
//
#include <hip/hip_runtime.h>

// ---------------------------------------------------------------------------
// GCN encoder, bf16 staging + MFMA GEMMs + bpermute-broadcast gather agg.
//   h  = relu(Agg(x@W1) + b1);  [mu|lv] = Agg(h@[Wmu|Wlv]) + bias
// Agg(p)[i] = dinv[i] * ( sum_{e: dst=i} p'[src] + p'[i] ), p' = p*dinv[row]
// dinv[src] folded into GEMM epilogue (p' = bf16(acc*dinv)).
// Agg: 4 nodes/wave, 16 lanes x 8ch dwordx4 (full 256B row/instr), bpermute
// broadcast, 16-deep load batching, idle slots read zeroed row n. R1/R7
// A/B (73% vs 36% occ, both 64us, FETCH 189MB) => this pattern is at the
// random-256B-line throughput wall; agg body frozen.
// R8: (a) agg_relu FUSED with GEMM2 — one WG's 16 aggregated rows form one
// 16x128 MFMA A-tile (LDS-staged, 136-padded); eliminates hbuf (51MB) and
// a launch. (b) k_prep merged into k_bin_count (blockIdx split). 8 launches.
// CSR build: LDS radix binning (bucket = dst>>7), zero global atomics.
// Requires n <= 131072 (n = 100000 here).
// ---------------------------------------------------------------------------

#define C_IN  256
#define HID   128
#define C_OUT 64
#define NBUCK 1024
#define P1WGS 256

typedef __attribute__((ext_vector_type(8))) short bf16x8;
typedef __attribute__((ext_vector_type(4))) float f32x4;

__device__ inline unsigned short f2bf(float f) {  // round-to-nearest-even
  unsigned u = __float_as_uint(f);
  unsigned r = u + 0x7FFF + ((u >> 16) & 1);
  return (unsigned short)(r >> 16);
}
__device__ inline float bflo(unsigned v) { return __uint_as_float(v << 16); }
__device__ inline float bfhi(unsigned v) { return __uint_as_float(v & 0xFFFF0000u); }

// ---------------- P1: bucket histogram (blocks 0..255) + weight prep ---------
__global__ __launch_bounds__(256) void k_count_prep(
    const int* __restrict__ dst, int* __restrict__ histmat, int E,
    const float* __restrict__ W1, const float* __restrict__ Wmu,
    const float* __restrict__ Wlv,
    unsigned short* __restrict__ bswz1, unsigned short* __restrict__ bswz2,
    unsigned* __restrict__ p1z, unsigned* __restrict__ p2z) {
  __shared__ int h[NBUCK];
  int tid = threadIdx.x;
  if (blockIdx.x < P1WGS) {
    for (int i = tid; i < NBUCK; i += 256) h[i] = 0;
    __syncthreads();
    for (int e = blockIdx.x * 256 + tid; e < E; e += P1WGS * 256)
      atomicAdd(&h[dst[e] >> 7], 1);
    __syncthreads();
    for (int i = tid; i < NBUCK; i += 256)
      histmat[blockIdx.x * NBUCK + i] = h[i];
    return;
  }
  // ---- prep branch: Bswz[s][t][L][j] = bf16(B[s*32+(L>>4)*8+j][t*16+(L&15)])
  int idx = (blockIdx.x - P1WGS) * 256 + tid;
  if (idx < 4096) {            // W1: (256/32)*8*64
    int L = idx & 63, t = (idx >> 6) & 7, s = idx >> 9;
    const float* srcp = W1 + (size_t)(s * 32 + ((L >> 4) << 3)) * 128 + t * 16 + (L & 15);
    unsigned short* dstp = bswz1 + (size_t)idx * 8;
#pragma unroll
    for (int j = 0; j < 8; j++) dstp[j] = f2bf(srcp[(size_t)j * 128]);
  } else if (idx < 6144) {     // [Wmu|Wlv]: (128/32)*8*64
    int id2 = idx - 4096;
    int L = id2 & 63, t = (id2 >> 6) & 7, s = id2 >> 9;
    int nn = t * 16 + (L & 15);
    int k0 = s * 32 + ((L >> 4) << 3);
    const float* W = (nn < C_OUT) ? (Wmu + nn) : (Wlv + (nn - C_OUT));
    unsigned short* dstp = bswz2 + (size_t)id2 * 8;
#pragma unroll
    for (int j = 0; j < 8; j++) dstp[j] = f2bf(W[(size_t)(k0 + j) * C_OUT]);
  } else if (idx < 6208) {     // zero row n of p1 (64 dwords)
    p1z[idx - 6144] = 0u;
  } else if (idx < 6272) {     // zero row n of p2
    p2z[idx - 6208] = 0u;
  }
}

// ---------------- P2: per-bucket exclusive scan across WGs (in place) --------
__global__ __launch_bounds__(256) void k_col_scan(int* __restrict__ histmat,
                                                  int* __restrict__ bucket_tot) {
  __shared__ int sh[P1WGS];
  int b = blockIdx.x;
  int t = threadIdx.x;
  int v = histmat[t * NBUCK + b];
  sh[t] = v; __syncthreads();
  for (int ofs = 1; ofs < P1WGS; ofs <<= 1) {
    int add = (t >= ofs) ? sh[t - ofs] : 0;
    __syncthreads();
    sh[t] += add;
    __syncthreads();
  }
  histmat[t * NBUCK + b] = sh[t] - v;  // exclusive
  if (t == P1WGS - 1) bucket_tot[b] = sh[t];
}

// ---------------- P3: bucket_start = exclusive scan of bucket_tot ------------
__global__ void k_bucket_scan(const int* __restrict__ bucket_tot,
                              int* __restrict__ bucket_start, int E) {
  __shared__ int sh[NBUCK];
  int t = threadIdx.x;
  int v = bucket_tot[t];
  sh[t] = v; __syncthreads();
  for (int ofs = 1; ofs < NBUCK; ofs <<= 1) {
    int add = (t >= ofs) ? sh[t - ofs] : 0;
    __syncthreads();
    sh[t] += add;
    __syncthreads();
  }
  bucket_start[t] = sh[t] - v;
  if (t == NBUCK - 1) bucket_start[NBUCK] = E;
}

// ---------------- P4: scatter edges into bucket-segmented array --------------
__global__ __launch_bounds__(256) void k_bin_scatter(const int* __restrict__ src,
                                                     const int* __restrict__ dst,
                                                     const int* __restrict__ histmat,
                                                     const int* __restrict__ bucket_start,
                                                     unsigned* __restrict__ binned, int E) {
  __shared__ int cur[NBUCK];
  int tid = threadIdx.x;
  for (int i = tid; i < NBUCK; i += 256)
    cur[i] = bucket_start[i] + histmat[blockIdx.x * NBUCK + i];
  __syncthreads();
  for (int e = blockIdx.x * 256 + tid; e < E; e += P1WGS * 256) {
    int d = dst[e];
    int pos = atomicAdd(&cur[d >> 7], 1);
    binned[pos] = (unsigned)src[e] | ((unsigned)(d & 127) << 17);
  }
}

// ---------------- P5: per-bucket deg/dinv/row_start + CSR fill ---------------
__global__ __launch_bounds__(256) void k_bucket_csr(const unsigned* __restrict__ binned,
                                                    const int* __restrict__ bucket_start,
                                                    int* __restrict__ row_start,
                                                    float* __restrict__ dinv,
                                                    int* __restrict__ csr_src,
                                                    int n, int E) {
  __shared__ int h[128], ls[128], c[128];
  int b = blockIdx.x, t = threadIdx.x;
  int start = bucket_start[b], end = bucket_start[b + 1];
  if (t < 128) h[t] = 0;
  __syncthreads();
  for (int e = start + t; e < end; e += 256)
    atomicAdd(&h[binned[e] >> 17], 1);
  __syncthreads();
  if (t < 128) ls[t] = h[t];
  __syncthreads();
  for (int ofs = 1; ofs < 128; ofs <<= 1) {
    int add = (t < 128 && t >= ofs) ? ls[t - ofs] : 0;
    __syncthreads();
    if (t < 128) ls[t] += add;
    __syncthreads();
  }
  if (t < 128) {
    int excl = ls[t] - h[t];
    ls[t] = excl;
    c[t] = excl;
    int node = b * 128 + t;
    if (node < n) {
      row_start[node] = start + excl;
      dinv[node] = rsqrtf((float)h[t] + 1.0f);
    }
  }
  if (b == 0 && t == 0) row_start[n] = E;
  __syncthreads();
  for (int e = start + t; e < end; e += 256) {
    unsigned v = binned[e];
    int pos = start + atomicAdd(&c[v >> 17], 1);
    csr_src[pos] = (int)(v & 0x1FFFF);
  }
}

// ---------------- MFMA GEMM (layer 1): C[M,128](bf16) = (A@B)*dinv[row] ------
template <typename AT, int K>
__global__ __launch_bounds__(256) void k_gemm_mfma(const AT* __restrict__ A,
                                                   const unsigned short* __restrict__ bswz,
                                                   unsigned short* __restrict__ C,
                                                   const float* __restrict__ dinv,
                                                   int M) {
  constexpr int NS = K / 32;
  int wave = threadIdx.x >> 6, lane = threadIdx.x & 63;
  int m0 = blockIdx.x * 64 + wave * 16;
  int lrow = lane & 15, lq = lane >> 4;
  int arow = m0 + lrow;
  bool rv = arow < M;
  const AT* ap = A + (size_t)(rv ? arow : 0) * K + lq * 8;

  auto loadA = [&](int s) -> bf16x8 {
    if (sizeof(AT) == 4) {
      const float* af = (const float*)ap + s * 32;
      float4 u0 = rv ? *(const float4*)(af) : float4{0, 0, 0, 0};
      float4 u1 = rv ? *(const float4*)(af + 4) : float4{0, 0, 0, 0};
      union { unsigned short us[8]; bf16x8 v; } tmp;
      tmp.us[0] = f2bf(u0.x); tmp.us[1] = f2bf(u0.y);
      tmp.us[2] = f2bf(u0.z); tmp.us[3] = f2bf(u0.w);
      tmp.us[4] = f2bf(u1.x); tmp.us[5] = f2bf(u1.y);
      tmp.us[6] = f2bf(u1.z); tmp.us[7] = f2bf(u1.w);
      return tmp.v;
    } else {
      const unsigned short* ab = (const unsigned short*)ap + s * 32;
      return rv ? *(const bf16x8*)(ab) : (bf16x8)(short)0;
    }
  };

  f32x4 acc[8];
#pragma unroll
  for (int t = 0; t < 8; t++) acc[t] = (f32x4){0.f, 0.f, 0.f, 0.f};

  bf16x8 a_cur = loadA(0);
  bf16x8 b_cur[8];
#pragma unroll
  for (int t = 0; t < 8; t++)
    b_cur[t] = *(const bf16x8*)(bswz + lane * 8 + t * 512);

#pragma unroll
  for (int s = 0; s < NS; ++s) {
    bf16x8 a_nxt = a_cur;
    bf16x8 b_nxt[8];
    if (s + 1 < NS) {
      a_nxt = loadA(s + 1);
      const unsigned short* bp = bswz + (size_t)(s + 1) * 4096 + lane * 8;
#pragma unroll
      for (int t = 0; t < 8; t++) b_nxt[t] = *(const bf16x8*)(bp + t * 512);
    }
#pragma unroll
    for (int t = 0; t < 8; t++)
      acc[t] = __builtin_amdgcn_mfma_f32_16x16x32_bf16(a_cur, b_cur[t], acc[t], 0, 0, 0);
    a_cur = a_nxt;
    if (s + 1 < NS) {
#pragma unroll
      for (int t = 0; t < 8; t++) b_cur[t] = b_nxt[t];
    }
  }
#pragma unroll
  for (int i = 0; i < 4; i++) {
    int rr = m0 + lq * 4 + i;
    if (rr < M) {
      float dsc = dinv[rr];           // fold dinv[src] into staged rows
      unsigned short* cp = C + (size_t)rr * 128 + lrow;
#pragma unroll
      for (int t = 0; t < 8; t++) cp[t * 16] = f2bf(acc[t][i] * dsc);
    }
  }
}

// ---------------- gather aggregation body: 4 nodes/wave, 16-deep batched -----
// p has n+1 rows of 128 bf16 (256B); row n is all-zero (idle-slot target).
#define AGG_V4_BODY                                                                 \
  int tid = threadIdx.x;                                                            \
  int wid4 = blockIdx.x * 4 + (tid >> 6); /* 4 waves/WG */                          \
  int lane = tid & 63;                                                              \
  int li = lane & 15;                                                               \
  int node = (wid4 << 2) + (lane >> 4);                                             \
  int rs = 0, re = -1;                                                              \
  if (node < n) { rs = row_start[node]; re = row_start[node + 1]; }                 \
  int mc = re - rs + 1; /* edges incl. self */                                      \
  mc = max(mc, __shfl_xor(mc, 16, 64));                                             \
  mc = max(mc, __shfl_xor(mc, 32, 64));                                             \
  int maxcnt = __builtin_amdgcn_readfirstlane(mc);                                  \
  const char* pb = (const char*)p;                                                  \
  unsigned loff = (unsigned)(li << 4);                                              \
  int vb = (lane & 48) << 2; /* byte idx of group base lane for bpermute */         \
  float acc0 = 0.f, acc1 = 0.f, acc2 = 0.f, acc3 = 0.f;                             \
  float acc4 = 0.f, acc5 = 0.f, acc6 = 0.f, acc7 = 0.f;                             \
  for (int t0 = 0; t0 < maxcnt; t0 += 16) {                                         \
    int s = rs + t0 + li;                                                           \
    int sl = n; /* zero row */                                                      \
    if (s < re) sl = csr[s];                                                        \
    else if (s == re) sl = node; /* self edge */                                    \
    unsigned o[16];                                                                 \
    _Pragma("unroll")                                                               \
    for (int k = 0; k < 16; ++k)                                                    \
      o[k] = ((unsigned)__builtin_amdgcn_ds_bpermute(vb + (k << 2), sl)) << 8;      \
    uint4 v[16];                                                                    \
    _Pragma("unroll")                                                               \
    for (int k = 0; k < 16; ++k)                                                    \
      v[k] = *(const uint4*)(pb + (o[k] + loff));                                   \
    _Pragma("unroll")                                                               \
    for (int k = 0; k < 16; ++k) {                                                  \
      acc0 += bflo(v[k].x); acc1 += bfhi(v[k].x);                                   \
      acc2 += bflo(v[k].y); acc3 += bfhi(v[k].y);                                   \
      acc4 += bflo(v[k].z); acc5 += bfhi(v[k].z);                                   \
      acc6 += bflo(v[k].w); acc7 += bfhi(v[k].w);                                   \
    }                                                                               \
  }

// ---------------- FUSED: agg+relu (layer1) -> 16x128 A-tile -> GEMM2 ---------
// WG = 4 waves x 4 nodes = 16 rows = one MFMA A-tile. Phase A: R7 agg body,
// relu+bias, bf16 round, stage to LDS (row stride 136 bf16: 272B -> rows
// shift 4 banks, only 2-way aliasing = free). Phase B: each wave computes 2
// of 8 column tiles (K=128, NS=4, 8 MFMA), stores p2 = bf16(acc*dinv[row]).
__global__ __launch_bounds__(256) void k_agg_gemm2(
    const unsigned short* __restrict__ p, const float* __restrict__ dinv,
    const int* __restrict__ row_start, const int* __restrict__ csr,
    const float* __restrict__ bias, const unsigned short* __restrict__ bswz2,
    unsigned short* __restrict__ p2, int n) {
  __shared__ unsigned short hs[16][136];
  AGG_V4_BODY
  int rwg = ((tid >> 6) << 2) + (lane >> 4);   // local row 0..15
  {
    uint4 u = {0u, 0u, 0u, 0u};
    if (node < n) {
      float di = dinv[node];
      float4 ba = *(const float4*)(bias + (li << 3));
      float4 bb = *(const float4*)(bias + (li << 3) + 4);
      float r0 = fmaxf(acc0 * di + ba.x, 0.f);
      float r1 = fmaxf(acc1 * di + ba.y, 0.f);
      float r2 = fmaxf(acc2 * di + ba.z, 0.f);
      float r3 = fmaxf(acc3 * di + ba.w, 0.f);
      float r4 = fmaxf(acc4 * di + bb.x, 0.f);
      float r5 = fmaxf(acc5 * di + bb.y, 0.f);
      float r6 = fmaxf(acc6 * di + bb.z, 0.f);
      float r7 = fmaxf(acc7 * di + bb.w, 0.f);
      u.x = (unsigned)f2bf(r0) | ((unsigned)f2bf(r1) << 16);
      u.y = (unsigned)f2bf(r2) | ((unsigned)f2bf(r3) << 16);
      u.z = (unsigned)f2bf(r4) | ((unsigned)f2bf(r5) << 16);
      u.w = (unsigned)f2bf(r6) | ((unsigned)f2bf(r7) << 16);
    }
    *(uint4*)(&hs[rwg][li << 3]) = u;          // 16B store, conflict-free
  }
  __syncthreads();

  // Phase B: GEMM2 over the WG's 16-row tile. wave w -> column tiles 2w, 2w+1
  int w = tid >> 6;
  int lrow = lane & 15, lq = lane >> 4;
  f32x4 g0 = (f32x4){0.f, 0.f, 0.f, 0.f};
  f32x4 g1 = (f32x4){0.f, 0.f, 0.f, 0.f};
#pragma unroll
  for (int s = 0; s < 4; ++s) {
    bf16x8 af = *(const bf16x8*)(&hs[lrow][(lq << 3) + s * 32]);
    const unsigned short* bp = bswz2 + s * 4096 + (w * 2) * 512 + lane * 8;
    bf16x8 bf0 = *(const bf16x8*)(bp);
    bf16x8 bf1 = *(const bf16x8*)(bp + 512);
    g0 = __builtin_amdgcn_mfma_f32_16x16x32_bf16(af, bf0, g0, 0, 0, 0);
    g1 = __builtin_amdgcn_mfma_f32_16x16x32_bf16(af, bf1, g1, 0, 0, 0);
  }
#pragma unroll
  for (int i = 0; i < 4; ++i) {
    int rr = blockIdx.x * 16 + (lq << 2) + i;
    if (rr < n) {
      float dsc = dinv[rr];
      unsigned short* cp = p2 + (size_t)rr * 128 + lrow;
      cp[(w * 2) * 16]     = f2bf(g0[i] * dsc);
      cp[(w * 2 + 1) * 16] = f2bf(g1[i] * dsc);
    }
  }
}

// ---------------- output aggregation (layer 2+3), R7 body --------------------
__global__ __launch_bounds__(256) void k_agg_out_bf(
    const unsigned short* __restrict__ p, const float* __restrict__ dinv,
    const int* __restrict__ row_start, const int* __restrict__ csr,
    const float* __restrict__ bmu, const float* __restrict__ blv,
    float* __restrict__ out, int n) {
  AGG_V4_BODY
  if (node < n) {
    float di = dinv[node];
    const float* bp = (li < 8) ? (bmu + (li << 3)) : (blv + ((li - 8) << 3));
    float* op = (li < 8) ? (out + (size_t)node * C_OUT + (li << 3))
                         : (out + (size_t)(n + node) * C_OUT + ((li - 8) << 3));
    float4 b0 = *(const float4*)(bp);
    float4 b1 = *(const float4*)(bp + 4);
    float4 o0 = {acc0 * di + b0.x, acc1 * di + b0.y,
                 acc2 * di + b0.z, acc3 * di + b0.w};
    float4 o1 = {acc4 * di + b1.x, acc5 * di + b1.y,
                 acc6 * di + b1.z, acc7 * di + b1.w};
    *(float4*)op = o0;
    *(float4*)(op + 4) = o1;
  }
}

// ---------------------------------------------------------------------------
extern "C" void kernel_launch(void* const* d_in, const int* in_sizes, int n_in,
                              void* d_out, int out_size, void* d_ws, size_t ws_size,
                              hipStream_t stream) {
  const float* x   = (const float*)d_in[0];
  const int*   ei  = (const int*)d_in[1];   // int32 on the wire (JAX x64 off)
  const float* W1  = (const float*)d_in[2];
  const float* b1  = (const float*)d_in[3];
  const float* Wmu = (const float*)d_in[4];
  const float* bmu = (const float*)d_in[5];
  const float* Wlv = (const float*)d_in[6];
  const float* blv = (const float*)d_in[7];
  float* out = (float*)d_out;

  const int n = in_sizes[0] / C_IN;
  const int E = in_sizes[1] / 2;
  const int* src = ei;
  const int* dst = ei + E;

  char* w = (char*)d_ws;
  auto alloc = [&](size_t bytes) -> void* {
    void* pp = (void*)w;
    w += (bytes + 255) & ~(size_t)255;
    return pp;
  };
  float*          dinv       = (float*)alloc((size_t)n * 4);
  int*            row_start  = (int*)alloc((size_t)(n + 1) * 4);
  int*            histmat    = (int*)alloc((size_t)P1WGS * NBUCK * 4);
  int*            bucket_tot = (int*)alloc((size_t)NBUCK * 4);
  int*            bucket_st  = (int*)alloc((size_t)(NBUCK + 1) * 4);
  unsigned*       binned     = (unsigned*)alloc((size_t)E * 4);
  int*            csr_src    = (int*)alloc((size_t)E * 4);
  unsigned short* bswz1      = (unsigned short*)alloc((size_t)C_IN * 128 * 2);
  unsigned short* bswz2      = (unsigned short*)alloc((size_t)HID * 128 * 2);
  unsigned short* p1         = (unsigned short*)alloc((size_t)(n + 1) * 128 * 2);
  unsigned short* p2         = (unsigned short*)alloc((size_t)(n + 1) * 128 * 2);
  (void)ws_size; (void)n_in; (void)out_size;

  const int TB = 256;
  const int gemm_bks = (n + 63) / 64;
  const int agg_bks = (n + 15) / 16;          // 4 nodes/wave, 4 waves/WG
  const int nbk_csr = (n + 127) / 128;        // buckets w/ valid nodes

  // ---- CSR build (LDS radix binning, no global atomics) + weight prep ----
  k_count_prep<<<P1WGS + 25, TB, 0, stream>>>(dst, histmat, E, W1, Wmu, Wlv,
                                              bswz1, bswz2,
                                              (unsigned*)(p1 + (size_t)n * 128),
                                              (unsigned*)(p2 + (size_t)n * 128));
  k_col_scan<<<NBUCK, TB, 0, stream>>>(histmat, bucket_tot);
  k_bucket_scan<<<1, NBUCK, 0, stream>>>(bucket_tot, bucket_st, E);
  k_bin_scatter<<<P1WGS, TB, 0, stream>>>(src, dst, histmat, bucket_st, binned, E);
  k_bucket_csr<<<nbk_csr, TB, 0, stream>>>(binned, bucket_st, row_start, dinv,
                                           csr_src, n, E);

  // ---- layer 1 GEMM ----
  k_gemm_mfma<float, C_IN><<<gemm_bks, TB, 0, stream>>>(x, bswz1, p1, dinv, n);

  // ---- layer 1 agg + relu fused with layer 2+3 GEMM ----
  k_agg_gemm2<<<agg_bks, TB, 0, stream>>>(p1, dinv, row_start, csr_src, b1,
                                          bswz2, p2, n);

  // ---- layer 2+3 output aggregation ----
  k_agg_out_bf<<<agg_bks, TB, 0, stream>>>(p2, dinv, row_start, csr_src, bmu, blv, out, n);
}

// Round 10
// 362.491 us; speedup vs baseline: 6.5269x; 1.0911x over previous
//
#include <hip/hip_runtime.h>

// ---------------------------------------------------------------------------
// GCN encoder, bf16 staging + MFMA GEMMs + bpermute-broadcast gather agg.
//   h  = relu(Agg(x@W1) + b1);  [mu|lv] = Agg(h@[Wmu|Wlv]) + bias
// Agg(p)[i] = dinv[i] * ( sum_{e: dst=i} p'[src] + p'[i] ), p' = p*dinv[row]
// dinv[src] folded into GEMM epilogue (p' = bf16(acc*dinv)).
// Agg: 4 nodes/wave, 16 lanes x 8ch dwordx4 (full 256B row/instr), bpermute
// broadcast, 16-deep load batching, idle slots read zeroed row n. R1/R7
// A/B (73% vs 36% occ, both 64us, FETCH 189MB) => random-256B-line wall;
// agg body frozen. R8: agg_relu fused with GEMM2 (74us, kept).
// R10 build rework (R9's cooperative grid-sync failed correctness; zero
// grid-sync here): 2 ordinary kernels replace the 5-kernel radix chain.
//  k_seg_bin: WG owns a contiguous edge block AND a private binned region
//    [wg*cap,...) -> LDS hist + scan + scatter, no cross-WG offsets needed.
//    Stores per-(seg,bucket) cnt/off. Prep WGs ride along. 1024 thr/WG.
//  k_bucket_build: WG = bucket; gathers its 256 runs into LDS, deg->scan->
//    csr at fixed bucket region b*CAPB (CAPB=4096 >> mean 2046, fixed input),
//    writes row_start/rdeg/dinv. Agg uses re = rs + rdeg[node].
// 5 launches. Requires n <= 131072 (n = 100000 here).
// ---------------------------------------------------------------------------

#define C_IN  256
#define HID   128
#define C_OUT 64
#define NBUCK 1024
#define NSEG  256
#define CAPB  4096
#define EBCAP 4608

typedef __attribute__((ext_vector_type(8))) short bf16x8;
typedef __attribute__((ext_vector_type(4))) float f32x4;

__device__ inline unsigned short f2bf(float f) {  // round-to-nearest-even
  unsigned u = __float_as_uint(f);
  unsigned r = u + 0x7FFF + ((u >> 16) & 1);
  return (unsigned short)(r >> 16);
}
__device__ inline float bflo(unsigned v) { return __uint_as_float(v << 16); }
__device__ inline float bfhi(unsigned v) { return __uint_as_float(v & 0xFFFF0000u); }

// ---------------- P1: per-segment bin (count+scan+scatter, private region) ---
// WGs [0,NSEG): segment binning. WGs [NSEG,NSEG+7): weight prep + zero rows.
__global__ __launch_bounds__(1024) void k_seg_bin(
    const int* __restrict__ src, const int* __restrict__ dst, int E, int cap,
    int* __restrict__ cnt_arr, int* __restrict__ off_arr,
    unsigned* __restrict__ binned,
    const float* __restrict__ W1, const float* __restrict__ Wmu,
    const float* __restrict__ Wlv,
    unsigned short* __restrict__ bswz1, unsigned short* __restrict__ bswz2,
    unsigned* __restrict__ p1z, unsigned* __restrict__ p2z) {
  int tid = threadIdx.x;
  int wg = blockIdx.x;
  if (wg >= NSEG) {
    // ---- prep branch: Bswz[s][t][L][j] = bf16(B[s*32+(L>>4)*8+j][t*16+(L&15)])
    int idx = (wg - NSEG) * 1024 + tid;
    if (idx < 4096) {            // W1: (256/32)*8*64
      int L = idx & 63, t = (idx >> 6) & 7, s = idx >> 9;
      const float* srcp = W1 + (size_t)(s * 32 + ((L >> 4) << 3)) * 128 + t * 16 + (L & 15);
      unsigned short* dstp = bswz1 + (size_t)idx * 8;
#pragma unroll
      for (int j = 0; j < 8; j++) dstp[j] = f2bf(srcp[(size_t)j * 128]);
    } else if (idx < 6144) {     // [Wmu|Wlv]: (128/32)*8*64
      int id2 = idx - 4096;
      int L = id2 & 63, t = (id2 >> 6) & 7, s = id2 >> 9;
      int nn = t * 16 + (L & 15);
      int k0 = s * 32 + ((L >> 4) << 3);
      const float* W = (nn < C_OUT) ? (Wmu + nn) : (Wlv + (nn - C_OUT));
      unsigned short* dstp = bswz2 + (size_t)id2 * 8;
#pragma unroll
      for (int j = 0; j < 8; j++) dstp[j] = f2bf(W[(size_t)(k0 + j) * C_OUT]);
    } else if (idx < 6208) {     // zero row n of p1 (64 dwords)
      p1z[idx - 6144] = 0u;
    } else if (idx < 6272) {     // zero row n of p2
      p2z[idx - 6208] = 0u;
    }
    return;
  }
  __shared__ int h[NBUCK], c[NBUCK];
  h[tid] = 0;                    // TB == NBUCK == 1024
  __syncthreads();
  int e0 = wg * cap;
  int e1 = e0 + cap; if (e1 > E) e1 = E;
  for (int e = e0 + tid; e < e1; e += 1024)
    atomicAdd(&h[dst[e] >> 7], 1);
  __syncthreads();
  int v = h[tid];
  for (int ofs = 1; ofs < NBUCK; ofs <<= 1) {
    int add = (tid >= ofs) ? h[tid - ofs] : 0;
    __syncthreads();
    h[tid] += add;
    __syncthreads();
  }
  int excl = h[tid] - v;         // exclusive prefix within this segment
  cnt_arr[(size_t)wg * NBUCK + tid] = v;
  off_arr[(size_t)wg * NBUCK + tid] = excl;
  c[tid] = excl;
  __syncthreads();
  for (int e = e0 + tid; e < e1; e += 1024) {
    int d = dst[e];
    int pos = e0 + atomicAdd(&c[d >> 7], 1);   // private region [e0, e1)
    binned[pos] = (unsigned)src[e] | ((unsigned)(d & 127) << 17);
  }
}

// ---------------- P2: per-bucket CSR (deg/dinv/row_start/rdeg + fill) --------
// WG = bucket b. Gathers its NSEG runs into LDS, then 2 passes in LDS.
// csr region for bucket b = [b*CAPB, b*CAPB + tot).
__global__ __launch_bounds__(256) void k_bucket_build(
    const unsigned* __restrict__ binned, const int* __restrict__ cnt_arr,
    const int* __restrict__ off_arr, int cap,
    int* __restrict__ row_start, int* __restrict__ rdeg,
    float* __restrict__ dinv, int* __restrict__ csr, int n) {
  int b = blockIdx.x, t = threadIdx.x;
  __shared__ unsigned eb[EBCAP];
  __shared__ int sc[256];
  __shared__ int deg[128], ex[128], cur[128];
  int cnt = cnt_arr[(size_t)t * NBUCK + b];    // run of segment t in bucket b
  int off = off_arr[(size_t)t * NBUCK + b];
  sc[t] = cnt;
  __syncthreads();
  for (int ofs = 1; ofs < 256; ofs <<= 1) {
    int add = (t >= ofs) ? sc[t - ofs] : 0;
    __syncthreads();
    sc[t] += add;
    __syncthreads();
  }
  int lbase = sc[t] - cnt;
  int tot = sc[255];
  // copy my segment's run into the LDS edge buffer
  const unsigned* srcp = binned + (size_t)t * cap + off;
  for (int j = 0; j < cnt; ++j) {
    int ppos = lbase + j;
    if (ppos < EBCAP) eb[ppos] = srcp[j];
  }
  if (t < 128) deg[t] = 0;
  __syncthreads();
  if (tot > EBCAP) tot = EBCAP;                // never expected (mean 2046)
  for (int e = t; e < tot; e += 256)
    atomicAdd(&deg[eb[e] >> 17], 1);
  __syncthreads();
  if (t < 128) ex[t] = deg[t];
  __syncthreads();
  for (int ofs = 1; ofs < 128; ofs <<= 1) {
    int add = (t < 128 && t >= ofs) ? ex[t - ofs] : 0;
    __syncthreads();
    if (t < 128) ex[t] += add;
    __syncthreads();
  }
  if (t < 128) {
    int excl = ex[t] - deg[t];
    cur[t] = excl;
    int node = b * 128 + t;
    if (node < n) {
      row_start[node] = b * CAPB + excl;
      rdeg[node] = deg[t];
      dinv[node] = rsqrtf((float)deg[t] + 1.0f);
    }
  }
  __syncthreads();
  for (int e = t; e < tot; e += 256) {
    unsigned v = eb[e];
    int d = (int)(v >> 17);
    int pos = atomicAdd(&cur[d], 1);
    csr[(size_t)b * CAPB + pos] = (int)(v & 0x1FFFF);
  }
}

// ---------------- MFMA GEMM (layer 1): C[M,128](bf16) = (A@B)*dinv[row] ------
template <typename AT, int K>
__global__ __launch_bounds__(256) void k_gemm_mfma(const AT* __restrict__ A,
                                                   const unsigned short* __restrict__ bswz,
                                                   unsigned short* __restrict__ C,
                                                   const float* __restrict__ dinv,
                                                   int M) {
  constexpr int NS = K / 32;
  int wave = threadIdx.x >> 6, lane = threadIdx.x & 63;
  int m0 = blockIdx.x * 64 + wave * 16;
  int lrow = lane & 15, lq = lane >> 4;
  int arow = m0 + lrow;
  bool rv = arow < M;
  const AT* ap = A + (size_t)(rv ? arow : 0) * K + lq * 8;

  auto loadA = [&](int s) -> bf16x8 {
    if (sizeof(AT) == 4) {
      const float* af = (const float*)ap + s * 32;
      float4 u0 = rv ? *(const float4*)(af) : float4{0, 0, 0, 0};
      float4 u1 = rv ? *(const float4*)(af + 4) : float4{0, 0, 0, 0};
      union { unsigned short us[8]; bf16x8 v; } tmp;
      tmp.us[0] = f2bf(u0.x); tmp.us[1] = f2bf(u0.y);
      tmp.us[2] = f2bf(u0.z); tmp.us[3] = f2bf(u0.w);
      tmp.us[4] = f2bf(u1.x); tmp.us[5] = f2bf(u1.y);
      tmp.us[6] = f2bf(u1.z); tmp.us[7] = f2bf(u1.w);
      return tmp.v;
    } else {
      const unsigned short* ab = (const unsigned short*)ap + s * 32;
      return rv ? *(const bf16x8*)(ab) : (bf16x8)(short)0;
    }
  };

  f32x4 acc[8];
#pragma unroll
  for (int t = 0; t < 8; t++) acc[t] = (f32x4){0.f, 0.f, 0.f, 0.f};

  bf16x8 a_cur = loadA(0);
  bf16x8 b_cur[8];
#pragma unroll
  for (int t = 0; t < 8; t++)
    b_cur[t] = *(const bf16x8*)(bswz + lane * 8 + t * 512);

#pragma unroll
  for (int s = 0; s < NS; ++s) {
    bf16x8 a_nxt = a_cur;
    bf16x8 b_nxt[8];
    if (s + 1 < NS) {
      a_nxt = loadA(s + 1);
      const unsigned short* bp = bswz + (size_t)(s + 1) * 4096 + lane * 8;
#pragma unroll
      for (int t = 0; t < 8; t++) b_nxt[t] = *(const bf16x8*)(bp + t * 512);
    }
#pragma unroll
    for (int t = 0; t < 8; t++)
      acc[t] = __builtin_amdgcn_mfma_f32_16x16x32_bf16(a_cur, b_cur[t], acc[t], 0, 0, 0);
    a_cur = a_nxt;
    if (s + 1 < NS) {
#pragma unroll
      for (int t = 0; t < 8; t++) b_cur[t] = b_nxt[t];
    }
  }
#pragma unroll
  for (int i = 0; i < 4; i++) {
    int rr = m0 + lq * 4 + i;
    if (rr < M) {
      float dsc = dinv[rr];           // fold dinv[src] into staged rows
      unsigned short* cp = C + (size_t)rr * 128 + lrow;
#pragma unroll
      for (int t = 0; t < 8; t++) cp[t * 16] = f2bf(acc[t][i] * dsc);
    }
  }
}

// ---------------- gather aggregation body: 4 nodes/wave, 16-deep batched -----
// p has n+1 rows of 128 bf16 (256B); row n is all-zero (idle-slot target).
// Row bounds: rs = row_start[node], re = rs + rdeg[node] (bucket-capacity CSR).
#define AGG_V4_BODY                                                                 \
  int tid = threadIdx.x;                                                            \
  int wid4 = blockIdx.x * 4 + (tid >> 6); /* 4 waves/WG */                          \
  int lane = tid & 63;                                                              \
  int li = lane & 15;                                                               \
  int node = (wid4 << 2) + (lane >> 4);                                             \
  int rs = 0, re = -1;                                                              \
  if (node < n) { rs = row_start[node]; re = rs + rdeg[node]; }                     \
  int mc = re - rs + 1; /* edges incl. self */                                      \
  mc = max(mc, __shfl_xor(mc, 16, 64));                                             \
  mc = max(mc, __shfl_xor(mc, 32, 64));                                             \
  int maxcnt = __builtin_amdgcn_readfirstlane(mc);                                  \
  const char* pb = (const char*)p;                                                  \
  unsigned loff = (unsigned)(li << 4);                                              \
  int vb = (lane & 48) << 2; /* byte idx of group base lane for bpermute */         \
  float acc0 = 0.f, acc1 = 0.f, acc2 = 0.f, acc3 = 0.f;                             \
  float acc4 = 0.f, acc5 = 0.f, acc6 = 0.f, acc7 = 0.f;                             \
  for (int t0 = 0; t0 < maxcnt; t0 += 16) {                                         \
    int s = rs + t0 + li;                                                           \
    int sl = n; /* zero row */                                                      \
    if (s < re) sl = csr[s];                                                        \
    else if (s == re) sl = node; /* self edge */                                    \
    unsigned o[16];                                                                 \
    _Pragma("unroll")                                                               \
    for (int k = 0; k < 16; ++k)                                                    \
      o[k] = ((unsigned)__builtin_amdgcn_ds_bpermute(vb + (k << 2), sl)) << 8;      \
    uint4 v[16];                                                                    \
    _Pragma("unroll")                                                               \
    for (int k = 0; k < 16; ++k)                                                    \
      v[k] = *(const uint4*)(pb + (o[k] + loff));                                   \
    _Pragma("unroll")                                                               \
    for (int k = 0; k < 16; ++k) {                                                  \
      acc0 += bflo(v[k].x); acc1 += bfhi(v[k].x);                                   \
      acc2 += bflo(v[k].y); acc3 += bfhi(v[k].y);                                   \
      acc4 += bflo(v[k].z); acc5 += bfhi(v[k].z);                                   \
      acc6 += bflo(v[k].w); acc7 += bfhi(v[k].w);                                   \
    }                                                                               \
  }

// ---------------- FUSED: agg+relu (layer1) -> 16x128 A-tile -> GEMM2 ---------
__global__ __launch_bounds__(256) void k_agg_gemm2(
    const unsigned short* __restrict__ p, const float* __restrict__ dinv,
    const int* __restrict__ row_start, const int* __restrict__ rdeg,
    const int* __restrict__ csr,
    const float* __restrict__ bias, const unsigned short* __restrict__ bswz2,
    unsigned short* __restrict__ p2, int n) {
  __shared__ unsigned short hs[16][136];
  AGG_V4_BODY
  int rwg = ((tid >> 6) << 2) + (lane >> 4);   // local row 0..15
  {
    uint4 u = {0u, 0u, 0u, 0u};
    if (node < n) {
      float di = dinv[node];
      float4 ba = *(const float4*)(bias + (li << 3));
      float4 bb = *(const float4*)(bias + (li << 3) + 4);
      float r0 = fmaxf(acc0 * di + ba.x, 0.f);
      float r1 = fmaxf(acc1 * di + ba.y, 0.f);
      float r2 = fmaxf(acc2 * di + ba.z, 0.f);
      float r3 = fmaxf(acc3 * di + ba.w, 0.f);
      float r4 = fmaxf(acc4 * di + bb.x, 0.f);
      float r5 = fmaxf(acc5 * di + bb.y, 0.f);
      float r6 = fmaxf(acc6 * di + bb.z, 0.f);
      float r7 = fmaxf(acc7 * di + bb.w, 0.f);
      u.x = (unsigned)f2bf(r0) | ((unsigned)f2bf(r1) << 16);
      u.y = (unsigned)f2bf(r2) | ((unsigned)f2bf(r3) << 16);
      u.z = (unsigned)f2bf(r4) | ((unsigned)f2bf(r5) << 16);
      u.w = (unsigned)f2bf(r6) | ((unsigned)f2bf(r7) << 16);
    }
    *(uint4*)(&hs[rwg][li << 3]) = u;          // 16B store, conflict-free
  }
  __syncthreads();

  // Phase B: GEMM2 over the WG's 16-row tile. wave w -> column tiles 2w, 2w+1
  int w = tid >> 6;
  int lrow = lane & 15, lq = lane >> 4;
  f32x4 g0 = (f32x4){0.f, 0.f, 0.f, 0.f};
  f32x4 g1 = (f32x4){0.f, 0.f, 0.f, 0.f};
#pragma unroll
  for (int s = 0; s < 4; ++s) {
    bf16x8 af = *(const bf16x8*)(&hs[lrow][(lq << 3) + s * 32]);
    const unsigned short* bp = bswz2 + s * 4096 + (w * 2) * 512 + lane * 8;
    bf16x8 bf0 = *(const bf16x8*)(bp);
    bf16x8 bf1 = *(const bf16x8*)(bp + 512);
    g0 = __builtin_amdgcn_mfma_f32_16x16x32_bf16(af, bf0, g0, 0, 0, 0);
    g1 = __builtin_amdgcn_mfma_f32_16x16x32_bf16(af, bf1, g1, 0, 0, 0);
  }
#pragma unroll
  for (int i = 0; i < 4; ++i) {
    int rr = blockIdx.x * 16 + (lq << 2) + i;
    if (rr < n) {
      float dsc = dinv[rr];
      unsigned short* cp = p2 + (size_t)rr * 128 + lrow;
      cp[(w * 2) * 16]     = f2bf(g0[i] * dsc);
      cp[(w * 2 + 1) * 16] = f2bf(g1[i] * dsc);
    }
  }
}

// ---------------- output aggregation (layer 2+3) -----------------------------
__global__ __launch_bounds__(256) void k_agg_out_bf(
    const unsigned short* __restrict__ p, const float* __restrict__ dinv,
    const int* __restrict__ row_start, const int* __restrict__ rdeg,
    const int* __restrict__ csr,
    const float* __restrict__ bmu, const float* __restrict__ blv,
    float* __restrict__ out, int n) {
  AGG_V4_BODY
  if (node < n) {
    float di = dinv[node];
    const float* bp = (li < 8) ? (bmu + (li << 3)) : (blv + ((li - 8) << 3));
    float* op = (li < 8) ? (out + (size_t)node * C_OUT + (li << 3))
                         : (out + (size_t)(n + node) * C_OUT + ((li - 8) << 3));
    float4 b0 = *(const float4*)(bp);
    float4 b1 = *(const float4*)(bp + 4);
    float4 o0 = {acc0 * di + b0.x, acc1 * di + b0.y,
                 acc2 * di + b0.z, acc3 * di + b0.w};
    float4 o1 = {acc4 * di + b1.x, acc5 * di + b1.y,
                 acc6 * di + b1.z, acc7 * di + b1.w};
    *(float4*)op = o0;
    *(float4*)(op + 4) = o1;
  }
}

// ---------------------------------------------------------------------------
extern "C" void kernel_launch(void* const* d_in, const int* in_sizes, int n_in,
                              void* d_out, int out_size, void* d_ws, size_t ws_size,
                              hipStream_t stream) {
  const float* x   = (const float*)d_in[0];
  const int*   ei  = (const int*)d_in[1];   // int32 on the wire (JAX x64 off)
  const float* W1  = (const float*)d_in[2];
  const float* b1  = (const float*)d_in[3];
  const float* Wmu = (const float*)d_in[4];
  const float* bmu = (const float*)d_in[5];
  const float* Wlv = (const float*)d_in[6];
  const float* blv = (const float*)d_in[7];
  float* out = (float*)d_out;

  const int n = in_sizes[0] / C_IN;
  const int E = in_sizes[1] / 2;
  const int* src = ei;
  const int* dst = ei + E;

  char* w = (char*)d_ws;
  auto alloc = [&](size_t bytes) -> void* {
    void* pp = (void*)w;
    w += (bytes + 255) & ~(size_t)255;
    return pp;
  };
  float*          dinv       = (float*)alloc((size_t)n * 4);
  int*            row_start  = (int*)alloc((size_t)n * 4);
  int*            rdeg       = (int*)alloc((size_t)n * 4);
  int*            cnt_arr    = (int*)alloc((size_t)NSEG * NBUCK * 4);
  int*            off_arr    = (int*)alloc((size_t)NSEG * NBUCK * 4);
  unsigned*       binned     = (unsigned*)alloc((size_t)E * 4);
  int*            csr        = (int*)alloc((size_t)NBUCK * CAPB * 4);
  unsigned short* bswz1      = (unsigned short*)alloc((size_t)C_IN * 128 * 2);
  unsigned short* bswz2      = (unsigned short*)alloc((size_t)HID * 128 * 2);
  unsigned short* p1         = (unsigned short*)alloc((size_t)(n + 1) * 128 * 2);
  unsigned short* p2         = (unsigned short*)alloc((size_t)(n + 1) * 128 * 2);
  (void)ws_size; (void)n_in; (void)out_size;

  const int TB = 256;
  const int cap = (E + NSEG - 1) / NSEG;       // edges per segment
  const int gemm_bks = (n + 63) / 64;
  const int agg_bks = (n + 15) / 16;           // 4 nodes/wave, 4 waves/WG
  const int nbk = (n + 127) / 128;             // buckets containing nodes

  // ---- build: 2 kernels, zero cross-WG coordination ----
  k_seg_bin<<<NSEG + 7, 1024, 0, stream>>>(src, dst, E, cap, cnt_arr, off_arr,
                                           binned, W1, Wmu, Wlv, bswz1, bswz2,
                                           (unsigned*)(p1 + (size_t)n * 128),
                                           (unsigned*)(p2 + (size_t)n * 128));
  k_bucket_build<<<nbk, TB, 0, stream>>>(binned, cnt_arr, off_arr, cap,
                                         row_start, rdeg, dinv, csr, n);

  // ---- layer 1 GEMM ----
  k_gemm_mfma<float, C_IN><<<gemm_bks, TB, 0, stream>>>(x, bswz1, p1, dinv, n);

  // ---- layer 1 agg + relu fused with layer 2+3 GEMM ----
  k_agg_gemm2<<<agg_bks, TB, 0, stream>>>(p1, dinv, row_start, rdeg, csr, b1,
                                          bswz2, p2, n);

  // ---- layer 2+3 output aggregation ----
  k_agg_out_bf<<<agg_bks, TB, 0, stream>>>(p2, dinv, row_start, rdeg, csr,
                                           bmu, blv, out, n);
}